// Round 1
// baseline (2968.774 us; speedup 1.0000x reference)
//
#include <hip/hip_runtime.h>

typedef unsigned short u16;
typedef unsigned int   u32;

using f32x4  = __attribute__((ext_vector_type(4))) float;
using bf16x8 = __attribute__((ext_vector_type(8))) short;  // 8 bf16 in 4 VGPRs (guide §3)

__device__ __forceinline__ float bf2f(u16 u){
  union { u32 i; float f; } x; x.i = ((u32)u) << 16; return x.f;
}
__device__ __forceinline__ u16 f2bf(float f){
  union { float f; u32 i; } x; x.f = f;
  u32 r = x.i + 0x7FFFu + ((x.i >> 16) & 1u);   // RNE
  return (u16)(r >> 16);
}
__device__ __forceinline__ int pack2(float a, float b){
  return (int)f2bf(a) | ((int)f2bf(b) << 16);
}

// window-order token m -> source row in x (roll by -3,-3 then 7x7 window partition)
__device__ __forceinline__ int rollmap(int m){
  int win = m / 49, n = m % 49;
  int b  = win >> 6, wi = win & 63;
  int wh = wi >> 3, ww = wi & 7;
  int r = n / 7, c = n % 7;
  int sh = wh*7 + r + 3; if (sh >= 56) sh -= 56;
  int sw = ww*7 + c + 3; if (sw >= 56) sw -= 56;
  return b*3136 + sh*56 + sw;
}

// ---------------- GEMM: C[M,N] = A[M,K] @ W[N,K]^T + bias ----------------
// AMODE 0: A bf16 row-major.  AMODE 1: A = fp32 x with roll/window row-gather (K must be 512).
// EPI 0: bf16 out. EPI 1: f32 out. EPI 2: bf16 out + exact GELU.
template<int EPI, int AMODE>
__global__ __launch_bounds__(256) void gemm_bt(const void* __restrict__ Ap,
      const u16* __restrict__ Bw, const float* __restrict__ bias,
      void* __restrict__ outp, int M, int N, int K)
{
  __shared__ __align__(16) u16 As[128*32];
  __shared__ __align__(16) u16 Bs[128*32];
  const int t    = threadIdx.x;
  const int lane = t & 63, wave = t >> 6;
  const int wm = wave >> 1, wn = wave & 1;
  const int bm = blockIdx.x, bn = blockIdx.y;

  // staging: thread t covers tile rows r0 = t/4 and r0+64, 16B chunk c16 = t&3
  const int c16 = t & 3;
  const int r0  = t >> 2;
  const int e0  = c16 * 8;

  const u16*   pA0_h = nullptr; const u16*   pA1_h = nullptr;
  const float* pA0_f = nullptr; const float* pA1_f = nullptr;
  if (AMODE == 0){
    const u16* A = (const u16*)Ap;
    pA0_h = A + (size_t)(bm*128 + r0     )*K + e0;
    pA1_h = A + (size_t)(bm*128 + r0 + 64)*K + e0;
  } else {
    const float* A = (const float*)Ap;
    pA0_f = A + (size_t)rollmap(bm*128 + r0     )*512 + e0;
    pA1_f = A + (size_t)rollmap(bm*128 + r0 + 64)*512 + e0;
  }
  const u16* pB0 = Bw + (size_t)(bn*128 + r0     )*K + e0;
  const u16* pB1 = Bw + (size_t)(bn*128 + r0 + 64)*K + e0;

  // LDS byte offsets, XOR swizzle: unit c16 stored at c16 ^ ((row>>1)&3) -> 2-way (free) on both sides
  const int sA0 = r0*64 + ((c16 ^ ((r0 >> 1) & 3)) * 16);
  const int sA1 = sA0 + 64*64;   // row+64: ((r+64)>>1)&3 unchanged

  const int lr = lane & 15, lk = lane >> 4;
  int offA[4], offB[4];
#pragma unroll
  for (int i = 0; i < 4; ++i){
    int ar = wm*64 + i*16 + lr;
    offA[i] = ar*64 + ((lk ^ ((ar >> 1) & 3)) * 16);
    int br = wn*64 + i*16 + lr;
    offB[i] = br*64 + ((lk ^ ((br >> 1) & 3)) * 16);
  }

  f32x4 acc[4][4];
#pragma unroll
  for (int i = 0; i < 4; ++i)
#pragma unroll
    for (int j = 0; j < 4; ++j) acc[i][j] = (f32x4){0.f, 0.f, 0.f, 0.f};

  for (int kt = 0; kt < K; kt += 32){
    int4 av0, av1;
    if (AMODE == 0){
      av0 = *(const int4*)(pA0_h + kt);
      av1 = *(const int4*)(pA1_h + kt);
    } else {
      float4 f0 = *(const float4*)(pA0_f + kt);
      float4 f1 = *(const float4*)(pA0_f + kt + 4);
      av0 = make_int4(pack2(f0.x,f0.y), pack2(f0.z,f0.w), pack2(f1.x,f1.y), pack2(f1.z,f1.w));
      float4 g0 = *(const float4*)(pA1_f + kt);
      float4 g1 = *(const float4*)(pA1_f + kt + 4);
      av1 = make_int4(pack2(g0.x,g0.y), pack2(g0.z,g0.w), pack2(g1.x,g1.y), pack2(g1.z,g1.w));
    }
    int4 bv0 = *(const int4*)(pB0 + kt);
    int4 bv1 = *(const int4*)(pB1 + kt);
    __syncthreads();                       // previous tile fully consumed
    *(int4*)((char*)As + sA0) = av0;
    *(int4*)((char*)As + sA1) = av1;
    *(int4*)((char*)Bs + sA0) = bv0;
    *(int4*)((char*)Bs + sA1) = bv1;
    __syncthreads();                       // tile visible
    bf16x8 fa[4], fb[4];
#pragma unroll
    for (int i = 0; i < 4; ++i){
      fa[i] = *(const bf16x8*)((const char*)As + offA[i]);
      fb[i] = *(const bf16x8*)((const char*)Bs + offB[i]);
    }
#pragma unroll
    for (int i = 0; i < 4; ++i)
#pragma unroll
      for (int j = 0; j < 4; ++j)
        acc[i][j] = __builtin_amdgcn_mfma_f32_16x16x32_bf16(fa[i], fb[j], acc[i][j], 0, 0, 0);
  }

#pragma unroll
  for (int i = 0; i < 4; ++i){
#pragma unroll
    for (int j = 0; j < 4; ++j){
      int cm = bm*128 + wm*64 + i*16 + (lane >> 4)*4;
      int cn = bn*128 + wn*64 + j*16 + (lane & 15);
      float bv = bias[cn];
#pragma unroll
      for (int r = 0; r < 4; ++r){
        float v = acc[i][j][r] + bv;
        if (EPI == 2) v = 0.5f * v * (1.f + erff(v * 0.70710678118f));
        if (EPI == 1) ((float*)outp)[(size_t)(cm + r)*N + cn] = v;
        else          ((u16*)  outp)[(size_t)(cm + r)*N + cn] = f2bf(v);
      }
    }
  }
}

// ---------------- attention: one block per (window, head) ----------------
__global__ __launch_bounds__(256) void attn_kernel(const u16* __restrict__ qkv,
      const float* __restrict__ rpb, const float* __restrict__ ls,
      u16* __restrict__ outp)
{
  __shared__ float qs[49*32];
  __shared__ float kts[32*52];   // k transposed [c][n]
  __shared__ float vs[49*32];
  __shared__ int   regid[49];
  const int blk = blockIdx.x;
  const int win = blk >> 4, h = blk & 15;
  const int tid = threadIdx.x, lane = tid & 63, wave = tid >> 6;
  const float scale = __expf(fminf(ls[h], 4.6051702f));  // ln(100)

  const u16* base = qkv + (size_t)win*49*1536 + h*32;
  for (int idx = tid; idx < 1568; idx += 256){
    int n = idx >> 5, c = idx & 31;
    qs [n*32 + c] = bf2f(base[(size_t)n*1536 + c]);
    kts[c*52 + n] = bf2f(base[(size_t)n*1536 + 512  + c]);
    vs [n*32 + c] = bf2f(base[(size_t)n*1536 + 1024 + c]);
  }
  if (tid < 49){
    int wi = win & 63, wh = wi >> 3, ww = wi & 7;
    int gh = wh*7 + tid/7, gw = ww*7 + tid%7;
    int rh = gh < 49 ? 0 : (gh < 53 ? 1 : 2);
    int rw = gw < 49 ? 0 : (gw < 53 ? 1 : 2);
    regid[tid] = rh*3 + rw;
  }
  __syncthreads();

  { // cosine normalization (scale folded into q)
    const int c = tid & 31;
    for (int rj = tid >> 5; rj < 98; rj += 8){
      if (rj < 49){
        float x = qs[rj*32 + c];
        float s = x*x;
#pragma unroll
        for (int off = 16; off; off >>= 1) s += __shfl_xor(s, off);
        qs[rj*32 + c] = x * (scale / fmaxf(sqrtf(s), 1e-12f));
      } else {
        int r = rj - 49;
        float x = kts[c*52 + r];
        float s = x*x;
#pragma unroll
        for (int off = 16; off; off >>= 1) s += __shfl_xor(s, off);
        kts[c*52 + r] = x / fmaxf(sqrtf(s), 1e-12f);
      }
    }
  }
  __syncthreads();

  const int j  = lane;
  const bool jv = j < 49;
  const int cc = lane & 31, half = lane >> 5;
  for (int i = wave; i < 49; i += 4){
    float s = -1e30f;
    if (jv){
      s = 0.f;
#pragma unroll 8
      for (int k2 = 0; k2 < 32; ++k2) s += qs[i*32 + k2] * kts[k2*52 + j];
      s += rpb[((size_t)h*49 + i)*49 + j];
      if (regid[i] != regid[j]) s -= 100.f;
    }
    float mx = s;
#pragma unroll
    for (int off = 32; off; off >>= 1) mx = fmaxf(mx, __shfl_xor(mx, off));
    float p = jv ? __expf(s - mx) : 0.f;
    float sum = p;
#pragma unroll
    for (int off = 32; off; off >>= 1) sum += __shfl_xor(sum, off);
    p /= sum;
    float acc = 0.f;
#pragma unroll 5
    for (int jj = 0; jj < 25; ++jj){
      int j2 = half ? (25 + jj) : jj;
      float pj = __shfl(p, j2 < 49 ? j2 : 0);
      if (j2 < 49) acc += pj * vs[j2*32 + cc];
    }
    acc += __shfl_xor(acc, 32);
    if (half == 0)
      outp[((size_t)win*49 + i)*512 + h*32 + cc] = f2bf(acc);
  }
}

// ---------------- LN kernels ----------------
__global__ __launch_bounds__(256) void ln1_kernel(const float* __restrict__ x,
      const float* __restrict__ y, const float* __restrict__ g, const float* __restrict__ bt,
      float* __restrict__ xout, u16* __restrict__ xbf)
{
  __shared__ float red[8];
  const int t = blockIdx.x;
  const int b = t / 3136, s = t % 3136;
  const int hh = s / 56, ww2 = s % 56;
  int ph = hh + 53; if (ph >= 56) ph -= 56;   // inverse roll (+3)
  int pw = ww2 + 53; if (pw >= 56) pw -= 56;
  const int win = b*64 + (ph/7)*8 + (pw/7);
  const int n   = (ph%7)*7 + (pw%7);
  const float* yr = y + ((size_t)win*49 + n)*512;
  const int c = threadIdx.x * 2;
  float2 v = *(const float2*)(yr + c);
  float sum = v.x + v.y, sq = v.x*v.x + v.y*v.y;
#pragma unroll
  for (int off = 32; off; off >>= 1){ sum += __shfl_xor(sum, off); sq += __shfl_xor(sq, off); }
  if ((threadIdx.x & 63) == 0){ red[threadIdx.x >> 6] = sum; red[(threadIdx.x >> 6) + 4] = sq; }
  __syncthreads();
  sum = red[0]+red[1]+red[2]+red[3];
  sq  = red[4]+red[5]+red[6]+red[7];
  const float mu  = sum * (1.f/512.f);
  const float inv = rsqrtf(fmaxf(sq * (1.f/512.f) - mu*mu, 0.f) + 1e-5f);
  const float* xr = x + (size_t)t*512;
  float2 xv = *(const float2*)(xr + c);
  float o0 = xv.x + (v.x - mu)*inv*g[c]   + bt[c];
  float o1 = xv.y + (v.y - mu)*inv*g[c+1] + bt[c+1];
  float* orow = xout + (size_t)t*512;
  orow[c] = o0; orow[c+1] = o1;
  *(u32*)(xbf + (size_t)t*512 + c) = (u32)f2bf(o0) | ((u32)f2bf(o1) << 16);
}

__global__ __launch_bounds__(256) void ln2_kernel(const u16* __restrict__ m,
      const float* __restrict__ g, const float* __restrict__ bt, float* __restrict__ out)
{
  __shared__ float red[8];
  const int t = blockIdx.x;
  const int c = threadIdx.x * 2;
  u32 u = *(const u32*)(m + (size_t)t*512 + c);
  float v0 = bf2f((u16)(u & 0xffff)), v1 = bf2f((u16)(u >> 16));
  float sum = v0 + v1, sq = v0*v0 + v1*v1;
#pragma unroll
  for (int off = 32; off; off >>= 1){ sum += __shfl_xor(sum, off); sq += __shfl_xor(sq, off); }
  if ((threadIdx.x & 63) == 0){ red[threadIdx.x >> 6] = sum; red[(threadIdx.x >> 6) + 4] = sq; }
  __syncthreads();
  sum = red[0]+red[1]+red[2]+red[3];
  sq  = red[4]+red[5]+red[6]+red[7];
  const float mu  = sum * (1.f/512.f);
  const float inv = rsqrtf(fmaxf(sq * (1.f/512.f) - mu*mu, 0.f) + 1e-5f);
  float* orow = out + (size_t)t*512;
  orow[c]   += (v0 - mu)*inv*g[c]   + bt[c];
  orow[c+1] += (v1 - mu)*inv*g[c+1] + bt[c+1];
}

// ---------------- tiny prep kernels ----------------
__global__ void cast_bf16_kernel(const float* __restrict__ in, u16* __restrict__ out, int n4){
  int i = blockIdx.x*256 + threadIdx.x;
  if (i >= n4) return;
  float4 v = *(const float4*)(in + (size_t)i*4);
  u32 lo = (u32)f2bf(v.x) | ((u32)f2bf(v.y) << 16);
  u32 hi = (u32)f2bf(v.z) | ((u32)f2bf(v.w) << 16);
  *(uint2*)(out + (size_t)i*4) = make_uint2(lo, hi);
}
__global__ void qkvbias_kernel(const float* __restrict__ qb, const float* __restrict__ vb,
                               float* __restrict__ out){
  int i = blockIdx.x*256 + threadIdx.x;
  if (i >= 1536) return;
  out[i] = i < 512 ? qb[i] : (i < 1024 ? 0.f : vb[i - 1024]);
}
__device__ __forceinline__ float cpb_coord(int d){
  float v = (float)(d - 6) * (8.f/6.f);
  float m = log2f(fabsf(v) + 1.f) * (1.f/3.f);     // log2(8)=3
  return v > 0.f ? m : (v < 0.f ? -m : 0.f);
}
__global__ void cpb_kernel(const float* __restrict__ w1, const float* __restrict__ b1,
                           const float* __restrict__ w2, float* __restrict__ btbl){
  int idx = blockIdx.x*256 + threadIdx.x;
  if (idx >= 169*16) return;
  int e = idx >> 4, h = idx & 15;
  float t0 = cpb_coord(e / 13), t1 = cpb_coord(e % 13);
  float acc = 0.f;
  for (int jj = 0; jj < 512; ++jj){
    float hid = fmaxf(t0*w1[jj*2] + t1*w1[jj*2+1] + b1[jj], 0.f);
    acc += hid * w2[h*512 + jj];
  }
  btbl[e*16 + h] = acc;
}
__global__ void rpb_kernel(const float* __restrict__ btbl, float* __restrict__ rpb){
  int idx = blockIdx.x*256 + threadIdx.x;
  if (idx >= 16*49*49) return;
  int hh = idx / 2401, ij = idx % 2401, i = ij / 49, j = ij % 49;
  int dr = i/7 - j/7 + 6, dc = i%7 - j%7 + 6;
  float bb = btbl[(dr*13 + dc)*16 + hh];
  rpb[idx] = 16.f / (1.f + __expf(-bb));
}

// ---------------- launch ----------------
extern "C" void kernel_launch(void* const* d_in, const int* in_sizes, int n_in,
                              void* d_out, int out_size, void* d_ws, size_t ws_size,
                              hipStream_t stream)
{
  const float* x    = (const float*)d_in[0];
  const float* qkvw = (const float*)d_in[1];
  const float* qb   = (const float*)d_in[2];
  const float* vb   = (const float*)d_in[3];
  const float* ls   = (const float*)d_in[4];
  const float* cw1  = (const float*)d_in[5];
  const float* cb1  = (const float*)d_in[6];
  const float* cw2  = (const float*)d_in[7];
  const float* pw   = (const float*)d_in[8];
  const float* pb   = (const float*)d_in[9];
  const float* n1g  = (const float*)d_in[10];
  const float* n1b  = (const float*)d_in[11];
  const float* f1w  = (const float*)d_in[12];
  const float* f1b  = (const float*)d_in[13];
  const float* f2w  = (const float*)d_in[14];
  const float* f2b  = (const float*)d_in[15];
  const float* n2g  = (const float*)d_in[16];
  const float* n2b  = (const float*)d_in[17];

  char* ws = (char*)d_ws;
  const size_t SZ_BIG = (size_t)100352 * 2048 * 2;   // 411 MB: qkv -> proj-out(f32) -> mlp hidden
  const size_t SZ_MID = (size_t)100352 * 512  * 2;   // 103 MB: attnout -> x2_bf16 -> m_bf16
  size_t o = SZ_BIG + SZ_MID;
  u16* wqkv  = (u16*)(ws + o); o += (size_t)1536*512*2;
  u16* wproj = (u16*)(ws + o); o += (size_t)512*512*2;
  u16* wfc1  = (u16*)(ws + o); o += (size_t)2048*512*2;
  u16* wfc2  = (u16*)(ws + o); o += (size_t)512*2048*2;
  float* qkvbias = (float*)(ws + o); o += 1536*4;
  float* btbl    = (float*)(ws + o); o += 2704*4;
  float* rpb     = (float*)(ws + o); o += 38416*4;

  u16*   big_h = (u16*)ws;
  float* y_f   = (float*)ws;
  u16*   mid   = (u16*)(ws + SZ_BIG);
  float* out   = (float*)d_out;

  cast_bf16_kernel<<<768,  256, 0, stream>>>(qkvw, wqkv, 1536*512/4);
  cast_bf16_kernel<<<256,  256, 0, stream>>>(pw,  wproj, 512*512/4);
  cast_bf16_kernel<<<1024, 256, 0, stream>>>(f1w, wfc1, 2048*512/4);
  cast_bf16_kernel<<<1024, 256, 0, stream>>>(f2w, wfc2, 512*2048/4);
  qkvbias_kernel<<<6, 256, 0, stream>>>(qb, vb, qkvbias);
  cpb_kernel<<<11, 256, 0, stream>>>(cw1, cb1, cw2, btbl);
  rpb_kernel<<<151, 256, 0, stream>>>(btbl, rpb);

  // QKV (fused roll+window gather + f32->bf16)
  gemm_bt<0,1><<<dim3(784,12), 256, 0, stream>>>((const void*)x, wqkv, qkvbias,
                                                 (void*)big_h, 100352, 1536, 512);
  attn_kernel<<<32768, 256, 0, stream>>>(big_h, rpb, ls, mid);
  // proj -> f32 (window order), reuses qkv region
  gemm_bt<1,0><<<dim3(784,4), 256, 0, stream>>>((const void*)mid, wproj, pb,
                                                (void*)y_f, 100352, 512, 512);
  // x2 = x + LN(unroll(y));  writes d_out (f32) + mid (bf16)
  ln1_kernel<<<100352, 256, 0, stream>>>(x, y_f, n1g, n1b, out, mid);
  // MLP
  gemm_bt<2,0><<<dim3(784,16), 256, 0, stream>>>((const void*)mid, wfc1, f1b,
                                                 (void*)big_h, 100352, 2048, 512);
  gemm_bt<0,0><<<dim3(784,4), 256, 0, stream>>>((const void*)big_h, wfc2, f2b,
                                                (void*)mid, 100352, 512, 2048);
  // out += LN(m)
  ln2_kernel<<<100352, 256, 0, stream>>>(mid, n2g, n2b, out);
}

// Round 2
// 1721.655 us; speedup vs baseline: 1.7244x; 1.7244x over previous
//
#include <hip/hip_runtime.h>

typedef unsigned short u16;
typedef unsigned int   u32;

using f32x4  = __attribute__((ext_vector_type(4))) float;
using bf16x8 = __attribute__((ext_vector_type(8))) short;  // 8 bf16 in 4 VGPRs

__device__ __forceinline__ float bf2f(u16 u){
  union { u32 i; float f; } x; x.i = ((u32)u) << 16; return x.f;
}
__device__ __forceinline__ u16 f2bf(float f){
  union { float f; u32 i; } x; x.f = f;
  u32 r = x.i + 0x7FFFu + ((x.i >> 16) & 1u);   // RNE
  return (u16)(r >> 16);
}
__device__ __forceinline__ int pack2(float a, float b){
  return (int)f2bf(a) | ((int)f2bf(b) << 16);
}

// async global->LDS, 16B per lane. LDS dest = wave-uniform base + lane*16 (HW).
__device__ __forceinline__ void glds16(const void* g, void* l){
  __builtin_amdgcn_global_load_lds(
      (const __attribute__((address_space(1))) unsigned int*)g,
      (__attribute__((address_space(3))) unsigned int*)(unsigned int)(unsigned long long)l,
      16, 0, 0);
}

// window-order token m -> source row in x (roll by -3,-3 then 7x7 window partition)
__device__ __forceinline__ int rollmap(int m){
  int win = m / 49, n = m % 49;
  int b  = win >> 6, wi = win & 63;
  int wh = wi >> 3, ww = wi & 7;
  int r = n / 7, c = n % 7;
  int sh = wh*7 + r + 3; if (sh >= 56) sh -= 56;
  int sw = ww*7 + c + 3; if (sw >= 56) sw -= 56;
  return b*3136 + sh*56 + sw;
}

// ---------------- GEMM: C[M,N] = A[M,K] @ W[N,K]^T + bias ----------------
// AMODE 0: A bf16 row-major (staged via global_load_lds, inverse-swizzled source).
// AMODE 1: A = fp32 x with roll/window row-gather + cvt (reg staging for A).
// EPI 0: bf16 out. EPI 1: f32 out. EPI 2: bf16 out + exact GELU.
template<int EPI, int AMODE>
__global__ __launch_bounds__(256) void gemm_bt(const void* __restrict__ Ap,
      const u16* __restrict__ Bw, const float* __restrict__ bias,
      void* __restrict__ outp, int M, int N, int K, int nbn)
{
  __shared__ __align__(16) u16 As[128*32];
  __shared__ __align__(16) u16 Bs[128*32];
  const int t    = threadIdx.x;
  const int lane = t & 63, wave = t >> 6;
  const int wm = wave >> 1, wn = wave & 1;

  // XCD-chunked block swizzle: each XCD gets a contiguous logical range;
  // bn fastest so blocks sharing an A-tile are adjacent (B is L2-resident).
  const int gl = ((blockIdx.x & 7) * ((int)gridDim.x >> 3)) + (blockIdx.x >> 3);
  const int bm = gl / nbn, bn = gl - bm*nbn;

  const int r0 = t >> 2;     // tile row 0..63 (and +64 for second half)
  const int sc = t & 3;      // this thread's LDS slot chunk (linear dest)
  const int dc = sc ^ ((r0 >> 1) & 3);   // data chunk to fetch -> lands swizzled

  const u16* gB0 = Bw + (size_t)(bn*128 + r0)*K + dc*8;
  const u16* gA0_h = nullptr;
  const float* pA0_f = nullptr; const float* pA1_f = nullptr;
  if constexpr (AMODE == 0){
    gA0_h = (const u16*)Ap + (size_t)(bm*128 + r0)*K + dc*8;
  } else {
    const float* A = (const float*)Ap;
    pA0_f = A + (size_t)rollmap(bm*128 + r0     )*512 + sc*8;
    pA1_f = A + (size_t)rollmap(bm*128 + r0 + 64)*512 + sc*8;
  }
  // AMODE1 ds_write slots (data chunk sc stored at slot sc^swz(row))
  const int sA0 = r0*64 + ((sc ^ ((r0 >> 1) & 3)) * 16);

  const int lr = lane & 15, lk = lane >> 4;
  int offA[4], offB[4];
#pragma unroll
  for (int i = 0; i < 4; ++i){
    int ar = wm*64 + i*16 + lr;
    offA[i] = ar*64 + ((lk ^ ((ar >> 1) & 3)) * 16);
    int br = wn*64 + i*16 + lr;
    offB[i] = br*64 + ((lk ^ ((br >> 1) & 3)) * 16);
  }

  f32x4 acc[4][4];
#pragma unroll
  for (int i = 0; i < 4; ++i)
#pragma unroll
    for (int j = 0; j < 4; ++j) acc[i][j] = (f32x4){0.f, 0.f, 0.f, 0.f};

  char* AsB = (char*)As;
  char* BsB = (char*)Bs;

  for (int kt = 0; kt < K; kt += 32){
    int4 av0, av1;
    if constexpr (AMODE == 1){
      float4 f0 = *(const float4*)(pA0_f + kt);
      float4 f1 = *(const float4*)(pA0_f + kt + 4);
      av0 = make_int4(pack2(f0.x,f0.y), pack2(f0.z,f0.w), pack2(f1.x,f1.y), pack2(f1.z,f1.w));
      float4 g0 = *(const float4*)(pA1_f + kt);
      float4 g1 = *(const float4*)(pA1_f + kt + 4);
      av1 = make_int4(pack2(g0.x,g0.y), pack2(g0.z,g0.w), pack2(g1.x,g1.y), pack2(g1.z,g1.w));
    }
    __syncthreads();                       // previous tile fully consumed
    if constexpr (AMODE == 0){
      glds16(gA0_h + kt,            AsB + wave*1024);
      glds16(gA0_h + kt + 64*K,     AsB + 4096 + wave*1024);
    } else {
      *(int4*)(AsB + sA0)        = av0;
      *(int4*)(AsB + sA0 + 4096) = av1;
    }
    glds16(gB0 + kt,        BsB + wave*1024);
    glds16(gB0 + kt + 64*K, BsB + 4096 + wave*1024);
    __syncthreads();                       // staged tile visible (vmcnt+lgkm drained)
    bf16x8 fa[4], fb[4];
#pragma unroll
    for (int i = 0; i < 4; ++i){
      fa[i] = *(const bf16x8*)(AsB + offA[i]);
      fb[i] = *(const bf16x8*)(BsB + offB[i]);
    }
#pragma unroll
    for (int i = 0; i < 4; ++i)
#pragma unroll
      for (int j = 0; j < 4; ++j)
        acc[i][j] = __builtin_amdgcn_mfma_f32_16x16x32_bf16(fa[i], fb[j], acc[i][j], 0, 0, 0);
  }

#pragma unroll
  for (int i = 0; i < 4; ++i){
#pragma unroll
    for (int j = 0; j < 4; ++j){
      int cm = bm*128 + wm*64 + i*16 + (lane >> 4)*4;
      int cn = bn*128 + wn*64 + j*16 + (lane & 15);
      float bv = bias[cn];
#pragma unroll
      for (int r = 0; r < 4; ++r){
        float v = acc[i][j][r] + bv;
        if (EPI == 2) v = 0.5f * v * (1.f + erff(v * 0.70710678118f));
        if (EPI == 1) ((float*)outp)[(size_t)(cm + r)*N + cn] = v;
        else          ((u16*)  outp)[(size_t)(cm + r)*N + cn] = f2bf(v);
      }
    }
  }
}

// ---------------- MFMA attention: 1 wave per (window, head), 4 waves/block ----
// 64x64 padded scores via 16 mfma; softmax on C-layout (row = one 16-lane group);
// P->LDS (pitch 144B); V staged transposed; PV via 16 mfma.
__global__ __launch_bounds__(256, 2) void attn_mfma(const u16* __restrict__ qkv,
      const float* __restrict__ rpb, const float* __restrict__ ls,
      u16* __restrict__ outp)
{
  __shared__ __align__(16) u16 Pl[4][64*72];   // per-wave P[64][72] (pitch 144B)
  __shared__ __align__(16) u16 Vl[4][32*72];   // per-wave Vt[32][72] (c-major)
  __shared__ unsigned char regid[64];
  const int tid  = threadIdx.x, lane = tid & 63, wave = tid >> 6;
  const int lc = lane & 15, lg = lane >> 4;
  const int pair = blockIdx.x*4 + wave;        // all 4 waves share one window
  const int win = pair >> 4, h = pair & 15;

  const u16* qb = qkv + (size_t)win*49*1536 + h*32;
  const u16* kb = qb + 512;
  const u16* vb = qb + 1024;

  if (tid < 49){
    int wi = win & 63, wh = wi >> 3, ww = wi & 7;
    int q7 = (tid*37) >> 8, r7 = tid - q7*7;
    int gh = wh*7 + q7, gw = ww*7 + r7;
    int rh = gh < 49 ? 0 : (gh < 53 ? 1 : 2);
    int rw = gw < 49 ? 0 : (gw < 53 ? 1 : 2);
    regid[tid] = (unsigned char)(rh*3 + rw);
  }

  // ---- stage V transposed: Vt[c][j], zero-padded j>=49 ----
  u16* V = &Vl[wave][0];
#pragma unroll
  for (int it = 0; it < 4; ++it){
    int ch = it*64 + lane;                 // 256 chunks = 64 rows x 4 octets
    int n = ch >> 2, oct = ch & 3;
    union { int4 i4; u16 s[8]; } v8;
    if (n < 49) v8.i4 = *(const int4*)(vb + (size_t)n*1536 + oct*8);
    else        v8.i4 = make_int4(0,0,0,0);
#pragma unroll
    for (int q = 0; q < 8; ++q) V[(oct*8 + q)*72 + n] = v8.s[q];
  }

  // ---- Q,K fragments direct from global + cosine normalize ----
  const float scale = __expf(fminf(ls[h], 4.6051702f));  // ln(100)
  bf16x8 qf[4], kf[4];
#pragma unroll
  for (int ti = 0; ti < 4; ++ti){
    const int n = ti*16 + lc;              // rows n>=49 are garbage; masked later
    {
      union { int4 i4; u16 s[8]; } raw;
      raw.i4 = *(const int4*)(qb + (size_t)n*1536 + lg*8);
      float f[8]; float ss = 0.f;
#pragma unroll
      for (int q = 0; q < 8; ++q){ f[q] = bf2f(raw.s[q]); ss += f[q]*f[q]; }
      ss += __shfl_xor(ss, 16); ss += __shfl_xor(ss, 32);
      const float inv = scale / fmaxf(sqrtf(ss), 1e-12f);
      union { short s[8]; bf16x8 v; } o;
#pragma unroll
      for (int q = 0; q < 8; ++q) o.s[q] = (short)f2bf(f[q]*inv);
      qf[ti] = o.v;
    }
    {
      union { int4 i4; u16 s[8]; } raw;
      raw.i4 = *(const int4*)(kb + (size_t)n*1536 + lg*8);
      float f[8]; float ss = 0.f;
#pragma unroll
      for (int q = 0; q < 8; ++q){ f[q] = bf2f(raw.s[q]); ss += f[q]*f[q]; }
      ss += __shfl_xor(ss, 16); ss += __shfl_xor(ss, 32);
      const float inv = 1.f / fmaxf(sqrtf(ss), 1e-12f);
      union { short s[8]; bf16x8 v; } o;
#pragma unroll
      for (int q = 0; q < 8; ++q) o.s[q] = (short)f2bf(f[q]*inv);
      kf[ti] = o.v;
    }
  }
  __syncthreads();   // regid (cross-wave) + V staging settled

  // ---- QK^T ----
  f32x4 acc[4][4];
#pragma unroll
  for (int i = 0; i < 4; ++i)
#pragma unroll
    for (int j = 0; j < 4; ++j) acc[i][j] = (f32x4){0.f,0.f,0.f,0.f};
#pragma unroll
  for (int i = 0; i < 4; ++i)
#pragma unroll
    for (int j = 0; j < 4; ++j)
      acc[i][j] = __builtin_amdgcn_mfma_f32_16x16x32_bf16(qf[i], kf[j], acc[i][j], 0, 0, 0);

  // ---- bias + mask + row softmax (row = one 16-lane group) -> P LDS ----
  u16* P = &Pl[wave][0];
  int rj[4];
#pragma unroll
  for (int tj = 0; tj < 4; ++tj){
    int j = tj*16 + lc;
    rj[tj] = (int)regid[j < 49 ? j : 0];
  }
  const float* rpbh = rpb + h*2401;
#pragma unroll
  for (int ti = 0; ti < 4; ++ti){
#pragma unroll
    for (int r = 0; r < 4; ++r){
      const int i = ti*16 + lg*4 + r;
      const bool iv = i < 49;
      const int ic = iv ? i : 0;
      const int ri = (int)regid[ic];
      const float* rrow = rpbh + ic*49;
      float sv[4];
#pragma unroll
      for (int tj = 0; tj < 4; ++tj){
        const int j = tj*16 + lc;
        float t2 = acc[ti][tj][r] + rrow[j < 49 ? j : 0];
        if (ri != rj[tj]) t2 -= 100.f;
        sv[tj] = (iv && j < 49) ? t2 : -1e30f;   // overwrite kills pad garbage/NaN
      }
      float mx = fmaxf(fmaxf(sv[0],sv[1]), fmaxf(sv[2],sv[3]));
      mx = fmaxf(mx, __shfl_xor(mx, 1));
      mx = fmaxf(mx, __shfl_xor(mx, 2));
      mx = fmaxf(mx, __shfl_xor(mx, 4));
      mx = fmaxf(mx, __shfl_xor(mx, 8));
      float p[4], sum = 0.f;
#pragma unroll
      for (int tj = 0; tj < 4; ++tj){ p[tj] = __expf(sv[tj] - mx); sum += p[tj]; }
      sum += __shfl_xor(sum, 1); sum += __shfl_xor(sum, 2);
      sum += __shfl_xor(sum, 4); sum += __shfl_xor(sum, 8);
      const float rs = __builtin_amdgcn_rcpf(sum);
#pragma unroll
      for (int tj = 0; tj < 4; ++tj) P[i*72 + tj*16 + lc] = f2bf(p[tj]*rs);
    }
  }
  __syncthreads();   // P visible (aligns waves; same-wave dep also settled)

  // ---- PV ----
  f32x4 o[4][2];
#pragma unroll
  for (int i = 0; i < 4; ++i){ o[i][0] = (f32x4){0.f,0.f,0.f,0.f}; o[i][1] = (f32x4){0.f,0.f,0.f,0.f}; }
#pragma unroll
  for (int ks = 0; ks < 2; ++ks){
    bf16x8 pa[4], vf[2];
#pragma unroll
    for (int ti = 0; ti < 4; ++ti)
      pa[ti] = *(const bf16x8*)((const char*)P + (ti*16 + lc)*144 + (ks*4 + lg)*16);
#pragma unroll
    for (int tc = 0; tc < 2; ++tc)
      vf[tc] = *(const bf16x8*)((const char*)V + (tc*16 + lc)*144 + (ks*4 + lg)*16);
#pragma unroll
    for (int ti = 0; ti < 4; ++ti)
#pragma unroll
      for (int tc = 0; tc < 2; ++tc)
        o[ti][tc] = __builtin_amdgcn_mfma_f32_16x16x32_bf16(pa[ti], vf[tc], o[ti][tc], 0, 0, 0);
  }

  // ---- store (window order) ----
#pragma unroll
  for (int ti = 0; ti < 4; ++ti){
#pragma unroll
    for (int tc = 0; tc < 2; ++tc){
#pragma unroll
      for (int r = 0; r < 4; ++r){
        const int i = ti*16 + lg*4 + r;
        if (i < 49)
          outp[((size_t)win*49 + i)*512 + h*32 + tc*16 + lc] = f2bf(o[ti][tc][r]);
      }
    }
  }
}

// ---------------- LN kernels ----------------
__global__ __launch_bounds__(256) void ln1_kernel(const float* __restrict__ x,
      const float* __restrict__ y, const float* __restrict__ g, const float* __restrict__ bt,
      float* __restrict__ xout, u16* __restrict__ xbf)
{
  __shared__ float red[8];
  const int t = blockIdx.x;
  const int b = t / 3136, s = t % 3136;
  const int hh = s / 56, ww2 = s % 56;
  int ph = hh + 53; if (ph >= 56) ph -= 56;   // inverse roll (+3)
  int pw = ww2 + 53; if (pw >= 56) pw -= 56;
  const int win = b*64 + (ph/7)*8 + (pw/7);
  const int n   = (ph%7)*7 + (pw%7);
  const float* yr = y + ((size_t)win*49 + n)*512;
  const int c = threadIdx.x * 2;
  float2 v = *(const float2*)(yr + c);
  float sum = v.x + v.y, sq = v.x*v.x + v.y*v.y;
#pragma unroll
  for (int off = 32; off; off >>= 1){ sum += __shfl_xor(sum, off); sq += __shfl_xor(sq, off); }
  if ((threadIdx.x & 63) == 0){ red[threadIdx.x >> 6] = sum; red[(threadIdx.x >> 6) + 4] = sq; }
  __syncthreads();
  sum = red[0]+red[1]+red[2]+red[3];
  sq  = red[4]+red[5]+red[6]+red[7];
  const float mu  = sum * (1.f/512.f);
  const float inv = rsqrtf(fmaxf(sq * (1.f/512.f) - mu*mu, 0.f) + 1e-5f);
  const float* xr = x + (size_t)t*512;
  float2 xv = *(const float2*)(xr + c);
  float o0 = xv.x + (v.x - mu)*inv*g[c]   + bt[c];
  float o1 = xv.y + (v.y - mu)*inv*g[c+1] + bt[c+1];
  float* orow = xout + (size_t)t*512;
  orow[c] = o0; orow[c+1] = o1;
  *(u32*)(xbf + (size_t)t*512 + c) = (u32)f2bf(o0) | ((u32)f2bf(o1) << 16);
}

__global__ __launch_bounds__(256) void ln2_kernel(const u16* __restrict__ m,
      const float* __restrict__ g, const float* __restrict__ bt, float* __restrict__ out)
{
  __shared__ float red[8];
  const int t = blockIdx.x;
  const int c = threadIdx.x * 2;
  u32 u = *(const u32*)(m + (size_t)t*512 + c);
  float v0 = bf2f((u16)(u & 0xffff)), v1 = bf2f((u16)(u >> 16));
  float sum = v0 + v1, sq = v0*v0 + v1*v1;
#pragma unroll
  for (int off = 32; off; off >>= 1){ sum += __shfl_xor(sum, off); sq += __shfl_xor(sq, off); }
  if ((threadIdx.x & 63) == 0){ red[threadIdx.x >> 6] = sum; red[(threadIdx.x >> 6) + 4] = sq; }
  __syncthreads();
  sum = red[0]+red[1]+red[2]+red[3];
  sq  = red[4]+red[5]+red[6]+red[7];
  const float mu  = sum * (1.f/512.f);
  const float inv = rsqrtf(fmaxf(sq * (1.f/512.f) - mu*mu, 0.f) + 1e-5f);
  float* orow = out + (size_t)t*512;
  orow[c]   += (v0 - mu)*inv*g[c]   + bt[c];
  orow[c+1] += (v1 - mu)*inv*g[c+1] + bt[c+1];
}

// ---------------- tiny prep kernels ----------------
__global__ void cast_bf16_kernel(const float* __restrict__ in, u16* __restrict__ out, int n4){
  int i = blockIdx.x*256 + threadIdx.x;
  if (i >= n4) return;
  float4 v = *(const float4*)(in + (size_t)i*4);
  u32 lo = (u32)f2bf(v.x) | ((u32)f2bf(v.y) << 16);
  u32 hi = (u32)f2bf(v.z) | ((u32)f2bf(v.w) << 16);
  *(uint2*)(out + (size_t)i*4) = make_uint2(lo, hi);
}
__global__ void qkvbias_kernel(const float* __restrict__ qb, const float* __restrict__ vb,
                               float* __restrict__ out){
  int i = blockIdx.x*256 + threadIdx.x;
  if (i >= 1536) return;
  out[i] = i < 512 ? qb[i] : (i < 1024 ? 0.f : vb[i - 1024]);
}
__device__ __forceinline__ float cpb_coord(int d){
  float v = (float)(d - 6) * (8.f/6.f);
  float m = log2f(fabsf(v) + 1.f) * (1.f/3.f);     // log2(8)=3
  return v > 0.f ? m : (v < 0.f ? -m : 0.f);
}
__global__ void cpb_kernel(const float* __restrict__ w1, const float* __restrict__ b1,
                           const float* __restrict__ w2, float* __restrict__ btbl){
  int idx = blockIdx.x*256 + threadIdx.x;
  if (idx >= 169*16) return;
  int e = idx >> 4, h = idx & 15;
  float t0 = cpb_coord(e / 13), t1 = cpb_coord(e % 13);
  float acc = 0.f;
  for (int jj = 0; jj < 512; ++jj){
    float hid = fmaxf(t0*w1[jj*2] + t1*w1[jj*2+1] + b1[jj], 0.f);
    acc += hid * w2[h*512 + jj];
  }
  btbl[e*16 + h] = acc;
}
__global__ void rpb_kernel(const float* __restrict__ btbl, float* __restrict__ rpb){
  int idx = blockIdx.x*256 + threadIdx.x;
  if (idx >= 16*49*49) return;
  int hh = idx / 2401, ij = idx % 2401, i = ij / 49, j = ij % 49;
  int dr = i/7 - j/7 + 6, dc = i%7 - j%7 + 6;
  float bb = btbl[(dr*13 + dc)*16 + hh];
  rpb[idx] = 16.f / (1.f + __expf(-bb));
}

// ---------------- launch ----------------
extern "C" void kernel_launch(void* const* d_in, const int* in_sizes, int n_in,
                              void* d_out, int out_size, void* d_ws, size_t ws_size,
                              hipStream_t stream)
{
  const float* x    = (const float*)d_in[0];
  const float* qkvw = (const float*)d_in[1];
  const float* qb   = (const float*)d_in[2];
  const float* vb   = (const float*)d_in[3];
  const float* ls   = (const float*)d_in[4];
  const float* cw1  = (const float*)d_in[5];
  const float* cb1  = (const float*)d_in[6];
  const float* cw2  = (const float*)d_in[7];
  const float* pw   = (const float*)d_in[8];
  const float* pb   = (const float*)d_in[9];
  const float* n1g  = (const float*)d_in[10];
  const float* n1b  = (const float*)d_in[11];
  const float* f1w  = (const float*)d_in[12];
  const float* f1b  = (const float*)d_in[13];
  const float* f2w  = (const float*)d_in[14];
  const float* f2b  = (const float*)d_in[15];
  const float* n2g  = (const float*)d_in[16];
  const float* n2b  = (const float*)d_in[17];

  char* ws = (char*)d_ws;
  const size_t SZ_BIG = (size_t)100352 * 2048 * 2;   // 411 MB: qkv -> proj-out(f32) -> mlp hidden
  const size_t SZ_MID = (size_t)100352 * 512  * 2;   // 103 MB: attnout -> x2_bf16 -> m_bf16
  size_t o = SZ_BIG + SZ_MID;
  u16* wqkv  = (u16*)(ws + o); o += (size_t)1536*512*2;
  u16* wproj = (u16*)(ws + o); o += (size_t)512*512*2;
  u16* wfc1  = (u16*)(ws + o); o += (size_t)2048*512*2;
  u16* wfc2  = (u16*)(ws + o); o += (size_t)512*2048*2;
  float* qkvbias = (float*)(ws + o); o += 1536*4;
  float* btbl    = (float*)(ws + o); o += 2704*4;
  float* rpb     = (float*)(ws + o); o += 38416*4;

  u16*   big_h = (u16*)ws;
  float* y_f   = (float*)ws;
  u16*   mid   = (u16*)(ws + SZ_BIG);
  float* out   = (float*)d_out;

  cast_bf16_kernel<<<768,  256, 0, stream>>>(qkvw, wqkv, 1536*512/4);
  cast_bf16_kernel<<<256,  256, 0, stream>>>(pw,  wproj, 512*512/4);
  cast_bf16_kernel<<<1024, 256, 0, stream>>>(f1w, wfc1, 2048*512/4);
  cast_bf16_kernel<<<1024, 256, 0, stream>>>(f2w, wfc2, 512*2048/4);
  qkvbias_kernel<<<6, 256, 0, stream>>>(qb, vb, qkvbias);
  cpb_kernel<<<11, 256, 0, stream>>>(cw1, cb1, cw2, btbl);
  rpb_kernel<<<151, 256, 0, stream>>>(btbl, rpb);

  // QKV (fused roll+window gather + f32->bf16), grid = bm x bn (bn fastest), XCD-chunked
  gemm_bt<0,1><<<784*12, 256, 0, stream>>>((const void*)x, wqkv, qkvbias,
                                           (void*)big_h, 100352, 1536, 512, 12);
  attn_mfma<<<8192, 256, 0, stream>>>(big_h, rpb, ls, mid);
  // proj -> f32 (window order), reuses qkv region
  gemm_bt<1,0><<<784*4, 256, 0, stream>>>((const void*)mid, wproj, pb,
                                          (void*)y_f, 100352, 512, 512, 4);
  // x2 = x + LN(unroll(y));  writes d_out (f32) + mid (bf16)
  ln1_kernel<<<100352, 256, 0, stream>>>(x, y_f, n1g, n1b, out, mid);
  // MLP
  gemm_bt<2,0><<<784*16, 256, 0, stream>>>((const void*)mid, wfc1, f1b,
                                           (void*)big_h, 100352, 2048, 512, 16);
  gemm_bt<0,0><<<784*4, 256, 0, stream>>>((const void*)big_h, wfc2, f2b,
                                          (void*)mid, 100352, 512, 2048, 4);
  // out += LN(m)
  ln2_kernel<<<100352, 256, 0, stream>>>(mid, n2g, n2b, out);
}

// Round 3
// 1617.406 us; speedup vs baseline: 1.8355x; 1.0645x over previous
//
#include <hip/hip_runtime.h>

typedef unsigned short u16;
typedef unsigned int   u32;

using f32x4  = __attribute__((ext_vector_type(4))) float;
using bf16x8 = __attribute__((ext_vector_type(8))) short;  // 8 bf16 in 4 VGPRs

__device__ __forceinline__ float bf2f(u16 u){
  union { u32 i; float f; } x; x.i = ((u32)u) << 16; return x.f;
}
__device__ __forceinline__ u16 f2bf(float f){
  union { float f; u32 i; } x; x.f = f;
  u32 r = x.i + 0x7FFFu + ((x.i >> 16) & 1u);   // RNE
  return (u16)(r >> 16);
}
// tanh-form GELU, safe at +/-inf exp: tanh(u) = 1 - 2/(e^{2u}+1)
__device__ __forceinline__ float gelu_f(float v){
  float u = 0.7978845608f * v * (1.f + 0.044715f*v*v);
  float e = __expf(2.f*u);
  return 0.5f*v*(2.f - 2.f/(e + 1.f));
}

// async global->LDS, 16B per lane. LDS dest = wave-uniform base + lane*16 (HW);
// global source address is per-lane (enables row-gather staging).
__device__ __forceinline__ void glds16(const void* g, void* l){
  __builtin_amdgcn_global_load_lds(
      (const __attribute__((address_space(1))) unsigned int*)g,
      (__attribute__((address_space(3))) unsigned int*)(unsigned int)(unsigned long long)l,
      16, 0, 0);
}

// window-order token m -> source row in x (roll by -3,-3 then 7x7 window partition)
__device__ __forceinline__ int rollmap(int m){
  int win = m / 49, n = m % 49;
  int b  = win >> 6, wi = win & 63;
  int wh = wi >> 3, ww = wi & 7;
  int r = n / 7, c = n % 7;
  int sh = wh*7 + r + 3; if (sh >= 56) sh -= 56;
  int sw = ww*7 + c + 3; if (sw >= 56) sw -= 56;
  return b*3136 + sh*56 + sw;
}

// ---------------- GEMM: C[M,N] = A[M,K] @ W[N,K]^T + bias ----------------
// AMODE 0: A bf16 row-major.  AMODE 2: A bf16 with roll/window row-gather.
// Both staged via global_load_lds (inverse-swizzled source, linear LDS dest).
// EPI 0: bf16 out. EPI 1: f32 out. EPI 2: bf16 out + GELU.
template<int EPI, int AMODE>
__global__ __launch_bounds__(256) void gemm_bt(const u16* __restrict__ A,
      const u16* __restrict__ Bw, const float* __restrict__ bias,
      void* __restrict__ outp, int M, int N, int K, int nbn)
{
  __shared__ __align__(16) u16 As[128*32];
  __shared__ __align__(16) u16 Bs[128*32];
  const int t    = threadIdx.x;
  const int lane = t & 63, wave = t >> 6;
  const int wm = wave >> 1, wn = wave & 1;

  // XCD-chunked block swizzle; bn fastest so blocks sharing an A-tile are adjacent.
  const int gl = ((blockIdx.x & 7) * ((int)gridDim.x >> 3)) + (blockIdx.x >> 3);
  const int bm = gl / nbn, bn = gl - bm*nbn;

  const int r0 = t >> 2;     // tile row 0..63 (and +64 for second half)
  const int sc = t & 3;      // this thread's LDS slot chunk (linear dest)
  const int dc = sc ^ ((r0 >> 1) & 3);   // data chunk to fetch -> lands swizzled

  const u16* gB0 = Bw + (size_t)(bn*128 + r0)*K + dc*8;
  const u16* gB1 = gB0 + (size_t)64*K;
  const u16* gA0; const u16* gA1;
  if constexpr (AMODE == 0){
    gA0 = A + (size_t)(bm*128 + r0)*K + dc*8;
    gA1 = gA0 + (size_t)64*K;
  } else {
    gA0 = A + (size_t)rollmap(bm*128 + r0     )*K + dc*8;
    gA1 = A + (size_t)rollmap(bm*128 + r0 + 64)*K + dc*8;
  }

  const int lr = lane & 15, lk = lane >> 4;
  int offA[4], offB[4];
#pragma unroll
  for (int i = 0; i < 4; ++i){
    int ar = wm*64 + i*16 + lr;
    offA[i] = ar*64 + ((lk ^ ((ar >> 1) & 3)) * 16);
    int br = wn*64 + i*16 + lr;
    offB[i] = br*64 + ((lk ^ ((br >> 1) & 3)) * 16);
  }

  f32x4 acc[4][4];
#pragma unroll
  for (int i = 0; i < 4; ++i)
#pragma unroll
    for (int j = 0; j < 4; ++j) acc[i][j] = (f32x4){0.f, 0.f, 0.f, 0.f};

  char* AsB = (char*)As;
  char* BsB = (char*)Bs;

  for (int kt = 0; kt < K; kt += 32){
    __syncthreads();                       // previous tile fully consumed
    glds16(gA0 + kt, AsB +        wave*1024);
    glds16(gA1 + kt, AsB + 4096 + wave*1024);
    glds16(gB0 + kt, BsB +        wave*1024);
    glds16(gB1 + kt, BsB + 4096 + wave*1024);
    __syncthreads();                       // staged tile visible
    bf16x8 fa[4], fb[4];
#pragma unroll
    for (int i = 0; i < 4; ++i){
      fa[i] = *(const bf16x8*)(AsB + offA[i]);
      fb[i] = *(const bf16x8*)(BsB + offB[i]);
    }
#pragma unroll
    for (int i = 0; i < 4; ++i)
#pragma unroll
      for (int j = 0; j < 4; ++j)
        acc[i][j] = __builtin_amdgcn_mfma_f32_16x16x32_bf16(fa[i], fb[j], acc[i][j], 0, 0, 0);
  }

#pragma unroll
  for (int i = 0; i < 4; ++i){
#pragma unroll
    for (int j = 0; j < 4; ++j){
      int cm = bm*128 + wm*64 + i*16 + (lane >> 4)*4;
      int cn = bn*128 + wn*64 + j*16 + (lane & 15);
      float bv = bias[cn];
#pragma unroll
      for (int r = 0; r < 4; ++r){
        float v = acc[i][j][r] + bv;
        if (EPI == 2) v = gelu_f(v);
        if (EPI == 1) ((float*)outp)[(size_t)(cm + r)*N + cn] = v;
        else          ((u16*)  outp)[(size_t)(cm + r)*N + cn] = f2bf(v);
      }
    }
  }
}

// ---------------- MFMA attention: 1 wave per (window, head), 4 waves/block ----
__global__ __launch_bounds__(256, 2) void attn_mfma(const u16* __restrict__ qkv,
      const float* __restrict__ rpb, const float* __restrict__ ls,
      u16* __restrict__ outp)
{
  __shared__ __align__(16) u16 Pl[4][64*72];   // per-wave P[64][72] (pitch 144B)
  __shared__ __align__(16) u16 Vl[4][32*72];   // per-wave Vt[32][72] (c-major)
  __shared__ unsigned char regid[64];
  const int tid  = threadIdx.x, lane = tid & 63, wave = tid >> 6;
  const int lc = lane & 15, lg = lane >> 4;
  const int pair = blockIdx.x*4 + wave;        // all 4 waves share one window
  const int win = pair >> 4, h = pair & 15;

  const u16* qb = qkv + (size_t)win*49*1536 + h*32;
  const u16* kb = qb + 512;
  const u16* vb = qb + 1024;

  if (tid < 49){
    int wi = win & 63, wh = wi >> 3, ww = wi & 7;
    int q7 = (tid*37) >> 8, r7 = tid - q7*7;
    int gh = wh*7 + q7, gw = ww*7 + r7;
    int rh = gh < 49 ? 0 : (gh < 53 ? 1 : 2);
    int rw = gw < 49 ? 0 : (gw < 53 ? 1 : 2);
    regid[tid] = (unsigned char)(rh*3 + rw);
  }

  // ---- stage V transposed: Vt[c][j], zero-padded j>=49 ----
  u16* V = &Vl[wave][0];
#pragma unroll
  for (int it = 0; it < 4; ++it){
    int ch = it*64 + lane;                 // 256 chunks = 64 rows x 4 octets
    int n = ch >> 2, oct = ch & 3;
    union { int4 i4; u16 s[8]; } v8;
    if (n < 49) v8.i4 = *(const int4*)(vb + (size_t)n*1536 + oct*8);
    else        v8.i4 = make_int4(0,0,0,0);
#pragma unroll
    for (int q = 0; q < 8; ++q) V[(oct*8 + q)*72 + n] = v8.s[q];
  }

  // ---- Q,K fragments direct from global + cosine normalize ----
  const float scale = __expf(fminf(ls[h], 4.6051702f));  // ln(100)
  bf16x8 qf[4], kf[4];
#pragma unroll
  for (int ti = 0; ti < 4; ++ti){
    const int n = ti*16 + lc;              // rows n>=49 are garbage; masked later
    {
      union { int4 i4; u16 s[8]; } raw;
      raw.i4 = *(const int4*)(qb + (size_t)n*1536 + lg*8);
      float f[8]; float ss = 0.f;
#pragma unroll
      for (int q = 0; q < 8; ++q){ f[q] = bf2f(raw.s[q]); ss += f[q]*f[q]; }
      ss += __shfl_xor(ss, 16); ss += __shfl_xor(ss, 32);
      const float inv = scale / fmaxf(sqrtf(ss), 1e-12f);
      union { short s[8]; bf16x8 v; } o;
#pragma unroll
      for (int q = 0; q < 8; ++q) o.s[q] = (short)f2bf(f[q]*inv);
      qf[ti] = o.v;
    }
    {
      union { int4 i4; u16 s[8]; } raw;
      raw.i4 = *(const int4*)(kb + (size_t)n*1536 + lg*8);
      float f[8]; float ss = 0.f;
#pragma unroll
      for (int q = 0; q < 8; ++q){ f[q] = bf2f(raw.s[q]); ss += f[q]*f[q]; }
      ss += __shfl_xor(ss, 16); ss += __shfl_xor(ss, 32);
      const float inv = 1.f / fmaxf(sqrtf(ss), 1e-12f);
      union { short s[8]; bf16x8 v; } o;
#pragma unroll
      for (int q = 0; q < 8; ++q) o.s[q] = (short)f2bf(f[q]*inv);
      kf[ti] = o.v;
    }
  }
  __syncthreads();   // regid (cross-wave) + V staging settled

  // ---- QK^T ----
  f32x4 acc[4][4];
#pragma unroll
  for (int i = 0; i < 4; ++i)
#pragma unroll
    for (int j = 0; j < 4; ++j) acc[i][j] = (f32x4){0.f,0.f,0.f,0.f};
#pragma unroll
  for (int i = 0; i < 4; ++i)
#pragma unroll
    for (int j = 0; j < 4; ++j)
      acc[i][j] = __builtin_amdgcn_mfma_f32_16x16x32_bf16(qf[i], kf[j], acc[i][j], 0, 0, 0);

  // ---- bias + mask + row softmax (row = one 16-lane group) -> P LDS ----
  u16* P = &Pl[wave][0];
  int rj[4];
#pragma unroll
  for (int tj = 0; tj < 4; ++tj){
    int j = tj*16 + lc;
    rj[tj] = (int)regid[j < 49 ? j : 0];
  }
  const float* rpbh = rpb + h*2401;
#pragma unroll
  for (int ti = 0; ti < 4; ++ti){
#pragma unroll
    for (int r = 0; r < 4; ++r){
      const int i = ti*16 + lg*4 + r;
      const bool iv = i < 49;
      const int ic = iv ? i : 0;
      const int ri = (int)regid[ic];
      const float* rrow = rpbh + ic*49;
      float sv[4];
#pragma unroll
      for (int tj = 0; tj < 4; ++tj){
        const int j = tj*16 + lc;
        float t2 = acc[ti][tj][r] + rrow[j < 49 ? j : 0];
        if (ri != rj[tj]) t2 -= 100.f;
        sv[tj] = (iv && j < 49) ? t2 : -1e30f;   // overwrite kills pad garbage/NaN
      }
      float mx = fmaxf(fmaxf(sv[0],sv[1]), fmaxf(sv[2],sv[3]));
      mx = fmaxf(mx, __shfl_xor(mx, 1));
      mx = fmaxf(mx, __shfl_xor(mx, 2));
      mx = fmaxf(mx, __shfl_xor(mx, 4));
      mx = fmaxf(mx, __shfl_xor(mx, 8));
      float p[4], sum = 0.f;
#pragma unroll
      for (int tj = 0; tj < 4; ++tj){ p[tj] = __expf(sv[tj] - mx); sum += p[tj]; }
      sum += __shfl_xor(sum, 1); sum += __shfl_xor(sum, 2);
      sum += __shfl_xor(sum, 4); sum += __shfl_xor(sum, 8);
      const float rs = __builtin_amdgcn_rcpf(sum);
#pragma unroll
      for (int tj = 0; tj < 4; ++tj) P[i*72 + tj*16 + lc] = f2bf(p[tj]*rs);
    }
  }
  __syncthreads();   // P visible

  // ---- PV ----
  f32x4 o[4][2];
#pragma unroll
  for (int i = 0; i < 4; ++i){ o[i][0] = (f32x4){0.f,0.f,0.f,0.f}; o[i][1] = (f32x4){0.f,0.f,0.f,0.f}; }
#pragma unroll
  for (int ks = 0; ks < 2; ++ks){
    bf16x8 pa[4], vf[2];
#pragma unroll
    for (int ti = 0; ti < 4; ++ti)
      pa[ti] = *(const bf16x8*)((const char*)P + (ti*16 + lc)*144 + (ks*4 + lg)*16);
#pragma unroll
    for (int tc = 0; tc < 2; ++tc)
      vf[tc] = *(const bf16x8*)((const char*)V + (tc*16 + lc)*144 + (ks*4 + lg)*16);
#pragma unroll
    for (int ti = 0; ti < 4; ++ti)
#pragma unroll
      for (int tc = 0; tc < 2; ++tc)
        o[ti][tc] = __builtin_amdgcn_mfma_f32_16x16x32_bf16(pa[ti], vf[tc], o[ti][tc], 0, 0, 0);
  }

  // ---- store (window order) ----
#pragma unroll
  for (int ti = 0; ti < 4; ++ti){
#pragma unroll
    for (int tc = 0; tc < 2; ++tc){
#pragma unroll
      for (int r = 0; r < 4; ++r){
        const int i = ti*16 + lg*4 + r;
        if (i < 49)
          outp[((size_t)win*49 + i)*512 + h*32 + tc*16 + lc] = f2bf(o[ti][tc][r]);
      }
    }
  }
}

// ---------------- LN kernels ----------------
__global__ __launch_bounds__(256) void ln1_kernel(const float* __restrict__ x,
      const u16* __restrict__ y, const float* __restrict__ g, const float* __restrict__ bt,
      float* __restrict__ xout, u16* __restrict__ xbf)
{
  __shared__ float red[8];
  const int t = blockIdx.x;
  const int b = t / 3136, s = t % 3136;
  const int hh = s / 56, ww2 = s % 56;
  int ph = hh + 53; if (ph >= 56) ph -= 56;   // inverse roll (+3)
  int pw = ww2 + 53; if (pw >= 56) pw -= 56;
  const int win = b*64 + (ph/7)*8 + (pw/7);
  const int n   = (ph%7)*7 + (pw%7);
  const u16* yr = y + ((size_t)win*49 + n)*512;
  const int c = threadIdx.x * 2;
  u32 u = *(const u32*)(yr + c);
  float vx = bf2f((u16)(u & 0xffff)), vy = bf2f((u16)(u >> 16));
  float sum = vx + vy, sq = vx*vx + vy*vy;
#pragma unroll
  for (int off = 32; off; off >>= 1){ sum += __shfl_xor(sum, off); sq += __shfl_xor(sq, off); }
  if ((threadIdx.x & 63) == 0){ red[threadIdx.x >> 6] = sum; red[(threadIdx.x >> 6) + 4] = sq; }
  __syncthreads();
  sum = red[0]+red[1]+red[2]+red[3];
  sq  = red[4]+red[5]+red[6]+red[7];
  const float mu  = sum * (1.f/512.f);
  const float inv = rsqrtf(fmaxf(sq * (1.f/512.f) - mu*mu, 0.f) + 1e-5f);
  const float* xr = x + (size_t)t*512;
  float2 xv = *(const float2*)(xr + c);
  float o0 = xv.x + (vx - mu)*inv*g[c]   + bt[c];
  float o1 = xv.y + (vy - mu)*inv*g[c+1] + bt[c+1];
  float* orow = xout + (size_t)t*512;
  orow[c] = o0; orow[c+1] = o1;
  *(u32*)(xbf + (size_t)t*512 + c) = (u32)f2bf(o0) | ((u32)f2bf(o1) << 16);
}

__global__ __launch_bounds__(256) void ln2_kernel(const u16* __restrict__ m,
      const float* __restrict__ g, const float* __restrict__ bt, float* __restrict__ out)
{
  __shared__ float red[8];
  const int t = blockIdx.x;
  const int c = threadIdx.x * 2;
  u32 u = *(const u32*)(m + (size_t)t*512 + c);
  float v0 = bf2f((u16)(u & 0xffff)), v1 = bf2f((u16)(u >> 16));
  float sum = v0 + v1, sq = v0*v0 + v1*v1;
#pragma unroll
  for (int off = 32; off; off >>= 1){ sum += __shfl_xor(sum, off); sq += __shfl_xor(sq, off); }
  if ((threadIdx.x & 63) == 0){ red[threadIdx.x >> 6] = sum; red[(threadIdx.x >> 6) + 4] = sq; }
  __syncthreads();
  sum = red[0]+red[1]+red[2]+red[3];
  sq  = red[4]+red[5]+red[6]+red[7];
  const float mu  = sum * (1.f/512.f);
  const float inv = rsqrtf(fmaxf(sq * (1.f/512.f) - mu*mu, 0.f) + 1e-5f);
  float* orow = out + (size_t)t*512;
  orow[c]   += (v0 - mu)*inv*g[c]   + bt[c];
  orow[c+1] += (v1 - mu)*inv*g[c+1] + bt[c+1];
}

// ---------------- tiny prep kernels ----------------
__global__ void cast_bf16_kernel(const float* __restrict__ in, u16* __restrict__ out, int n4){
  int i = blockIdx.x*256 + threadIdx.x;
  if (i >= n4) return;
  float4 v = *(const float4*)(in + (size_t)i*4);
  u32 lo = (u32)f2bf(v.x) | ((u32)f2bf(v.y) << 16);
  u32 hi = (u32)f2bf(v.z) | ((u32)f2bf(v.w) << 16);
  *(uint2*)(out + (size_t)i*4) = make_uint2(lo, hi);
}
__global__ void qkvbias_kernel(const float* __restrict__ qb, const float* __restrict__ vb,
                               float* __restrict__ out){
  int i = blockIdx.x*256 + threadIdx.x;
  if (i >= 1536) return;
  out[i] = i < 512 ? qb[i] : (i < 1024 ? 0.f : vb[i - 1024]);
}
__device__ __forceinline__ float cpb_coord(int d){
  float v = (float)(d - 6) * (8.f/6.f);
  float m = log2f(fabsf(v) + 1.f) * (1.f/3.f);     // log2(8)=3
  return v > 0.f ? m : (v < 0.f ? -m : 0.f);
}
__global__ void cpb_kernel(const float* __restrict__ w1, const float* __restrict__ b1,
                           const float* __restrict__ w2, float* __restrict__ btbl){
  int idx = blockIdx.x*256 + threadIdx.x;
  if (idx >= 169*16) return;
  int e = idx >> 4, h = idx & 15;
  float t0 = cpb_coord(e / 13), t1 = cpb_coord(e % 13);
  float acc = 0.f;
  for (int jj = 0; jj < 512; ++jj){
    float hid = fmaxf(t0*w1[jj*2] + t1*w1[jj*2+1] + b1[jj], 0.f);
    acc += hid * w2[h*512 + jj];
  }
  btbl[e*16 + h] = acc;
}
__global__ void rpb_kernel(const float* __restrict__ btbl, float* __restrict__ rpb){
  int idx = blockIdx.x*256 + threadIdx.x;
  if (idx >= 16*49*49) return;
  int hh = idx / 2401, ij = idx % 2401, i = ij / 49, j = ij % 49;
  int dr = i/7 - j/7 + 6, dc = i%7 - j%7 + 6;
  float bb = btbl[(dr*13 + dc)*16 + hh];
  rpb[idx] = 16.f / (1.f + __expf(-bb));
}

// ---------------- launch ----------------
extern "C" void kernel_launch(void* const* d_in, const int* in_sizes, int n_in,
                              void* d_out, int out_size, void* d_ws, size_t ws_size,
                              hipStream_t stream)
{
  const float* x    = (const float*)d_in[0];
  const float* qkvw = (const float*)d_in[1];
  const float* qb   = (const float*)d_in[2];
  const float* vb   = (const float*)d_in[3];
  const float* ls   = (const float*)d_in[4];
  const float* cw1  = (const float*)d_in[5];
  const float* cb1  = (const float*)d_in[6];
  const float* cw2  = (const float*)d_in[7];
  const float* pw   = (const float*)d_in[8];
  const float* pb   = (const float*)d_in[9];
  const float* n1g  = (const float*)d_in[10];
  const float* n1b  = (const float*)d_in[11];
  const float* f1w  = (const float*)d_in[12];
  const float* f1b  = (const float*)d_in[13];
  const float* f2w  = (const float*)d_in[14];
  const float* f2b  = (const float*)d_in[15];
  const float* n2g  = (const float*)d_in[16];
  const float* n2b  = (const float*)d_in[17];

  char* ws = (char*)d_ws;
  const size_t SZ_BIG = (size_t)100352 * 2048 * 2;   // 411 MB big region
  const size_t SZ_MID = (size_t)100352 * 512  * 2;   // 103 MB mid region
  size_t o = SZ_BIG + SZ_MID;
  u16* wqkv  = (u16*)(ws + o); o += (size_t)1536*512*2;
  u16* wproj = (u16*)(ws + o); o += (size_t)512*512*2;
  u16* wfc1  = (u16*)(ws + o); o += (size_t)2048*512*2;
  u16* wfc2  = (u16*)(ws + o); o += (size_t)512*2048*2;
  float* qkvbias = (float*)(ws + o); o += 1536*4;
  float* btbl    = (float*)(ws + o); o += 2704*4;
  float* rpb     = (float*)(ws + o); o += 38416*4;

  // big-region phases: [xbf 103MB | qkv 308MB] -> [y_h 103MB] -> [fc1-out 411MB]
  u16*   xbf   = (u16*)ws;
  u16*   qkvo  = (u16*)(ws + (size_t)100352*512*2);
  u16*   y_h   = (u16*)ws;
  u16*   big_h = (u16*)ws;
  u16*   mid   = (u16*)(ws + SZ_BIG);
  float* out   = (float*)d_out;

  cast_bf16_kernel<<<768,  256, 0, stream>>>(qkvw, wqkv, 1536*512/4);
  cast_bf16_kernel<<<256,  256, 0, stream>>>(pw,  wproj, 512*512/4);
  cast_bf16_kernel<<<1024, 256, 0, stream>>>(f1w, wfc1, 2048*512/4);
  cast_bf16_kernel<<<1024, 256, 0, stream>>>(f2w, wfc2, 512*2048/4);
  qkvbias_kernel<<<6, 256, 0, stream>>>(qb, vb, qkvbias);
  cpb_kernel<<<11, 256, 0, stream>>>(cw1, cb1, cw2, btbl);
  rpb_kernel<<<151, 256, 0, stream>>>(btbl, rpb);
  cast_bf16_kernel<<<50176, 256, 0, stream>>>(x, xbf, 100352*512/4);

  // QKV: row-gathered A (roll+window fused), gload_lds staging
  gemm_bt<0,2><<<784*12, 256, 0, stream>>>(xbf, wqkv, qkvbias,
                                           (void*)qkvo, 100352, 1536, 512, 12);
  attn_mfma<<<8192, 256, 0, stream>>>(qkvo, rpb, ls, mid);
  // proj -> bf16 (window order)
  gemm_bt<0,0><<<784*4, 256, 0, stream>>>(mid, wproj, pb,
                                          (void*)y_h, 100352, 512, 512, 4);
  // x2 = x + LN(unroll(y));  writes d_out (f32) + mid (bf16)
  ln1_kernel<<<100352, 256, 0, stream>>>(x, y_h, n1g, n1b, out, mid);
  // MLP
  gemm_bt<2,0><<<784*16, 256, 0, stream>>>(mid, wfc1, f1b,
                                           (void*)big_h, 100352, 2048, 512, 16);
  gemm_bt<0,0><<<784*4, 256, 0, stream>>>(big_h, wfc2, f2b,
                                          (void*)mid, 100352, 512, 2048, 4);
  // out += LN(m)
  ln2_kernel<<<100352, 256, 0, stream>>>(mid, n2g, n2b, out);
}

// Round 4
// 1503.566 us; speedup vs baseline: 1.9745x; 1.0757x over previous
//
#include <hip/hip_runtime.h>

typedef unsigned short u16;
typedef unsigned int   u32;

using f32x4  = __attribute__((ext_vector_type(4))) float;
using bf16x8 = __attribute__((ext_vector_type(8))) short;  // 8 bf16 in 4 VGPRs

__device__ __forceinline__ float bf2f(u16 u){
  union { u32 i; float f; } x; x.i = ((u32)u) << 16; return x.f;
}
__device__ __forceinline__ u16 f2bf(float f){
  union { float f; u32 i; } x; x.f = f;
  u32 r = x.i + 0x7FFFu + ((x.i >> 16) & 1u);   // RNE
  return (u16)(r >> 16);
}
// tanh-form GELU, safe at +/-inf exp: tanh(u) = 1 - 2/(e^{2u}+1)
__device__ __forceinline__ float gelu_f(float v){
  float u = 0.7978845608f * v * (1.f + 0.044715f*v*v);
  float e = __expf(2.f*u);
  return 0.5f*v*(2.f - 2.f/(e + 1.f));
}

// async global->LDS, 16B per lane. LDS dest = wave-uniform base + lane*16 (HW);
// global source address is per-lane (enables row-gather staging).
__device__ __forceinline__ void glds16(const void* g, void* l){
  __builtin_amdgcn_global_load_lds(
      (const __attribute__((address_space(1))) unsigned int*)g,
      (__attribute__((address_space(3))) unsigned int*)(unsigned int)(unsigned long long)l,
      16, 0, 0);
}

// window-order token m -> source row in x (roll by -3,-3 then 7x7 window partition)
__device__ __forceinline__ int rollmap(int m){
  int win = m / 49, n = m % 49;
  int b  = win >> 6, wi = win & 63;
  int wh = wi >> 3, ww = wi & 7;
  int r = n / 7, c = n % 7;
  int sh = wh*7 + r + 3; if (sh >= 56) sh -= 56;
  int sw = ww*7 + c + 3; if (sw >= 56) sw -= 56;
  return b*3136 + sh*56 + sw;
}

// ---------------- GEMM: C[M,N] = A[M,K] @ W[N,K]^T + bias ----------------
// AMODE 0: A bf16 row-major.  AMODE 2: A bf16 with roll/window row-gather.
// Staged via global_load_lds into DOUBLE-BUFFERED LDS: stage(t+1) issued
// before compute(t); the single end-of-iter barrier overlaps HBM latency
// with the MFMA phase (T3 minimal 2-phase).
// EPI 0: bf16 out. EPI 1: f32 out. EPI 2: bf16 out + GELU.
template<int EPI, int AMODE>
__global__ __launch_bounds__(256) void gemm_bt(const u16* __restrict__ A,
      const u16* __restrict__ Bw, const float* __restrict__ bias,
      void* __restrict__ outp, int M, int N, int K, int nbn)
{
  __shared__ __align__(16) u16 As[2*128*32];   // 16 KB (2 bufs)
  __shared__ __align__(16) u16 Bs[2*128*32];   // 16 KB
  const int t    = threadIdx.x;
  const int lane = t & 63, wave = t >> 6;
  const int wm = wave >> 1, wn = wave & 1;

  // XCD-chunked block swizzle; bn fastest so blocks sharing an A-tile are adjacent.
  const int gl = ((blockIdx.x & 7) * ((int)gridDim.x >> 3)) + (blockIdx.x >> 3);
  const int bm = gl / nbn, bn = gl - bm*nbn;

  const int r0 = t >> 2;     // tile row 0..63 (and +64 for second half)
  const int sc = t & 3;      // this thread's LDS slot chunk (linear dest)
  const int dc = sc ^ ((r0 >> 1) & 3);   // data chunk to fetch -> lands swizzled

  const u16* gB0 = Bw + (size_t)(bn*128 + r0)*K + dc*8;
  const u16* gB1 = gB0 + (size_t)64*K;
  const u16* gA0; const u16* gA1;
  if constexpr (AMODE == 0){
    gA0 = A + (size_t)(bm*128 + r0)*K + dc*8;
    gA1 = gA0 + (size_t)64*K;
  } else {
    gA0 = A + (size_t)rollmap(bm*128 + r0     )*K + dc*8;
    gA1 = A + (size_t)rollmap(bm*128 + r0 + 64)*K + dc*8;
  }

  const int lr = lane & 15, lk = lane >> 4;
  int offA[4], offB[4];
#pragma unroll
  for (int i = 0; i < 4; ++i){
    int ar = wm*64 + i*16 + lr;
    offA[i] = ar*64 + ((lk ^ ((ar >> 1) & 3)) * 16);
    int br = wn*64 + i*16 + lr;
    offB[i] = br*64 + ((lk ^ ((br >> 1) & 3)) * 16);
  }

  f32x4 acc[4][4];
#pragma unroll
  for (int i = 0; i < 4; ++i)
#pragma unroll
    for (int j = 0; j < 4; ++j) acc[i][j] = (f32x4){0.f, 0.f, 0.f, 0.f};

  char* AsB = (char*)As;
  char* BsB = (char*)Bs;

  // prologue: stage tile 0 into buf 0
  glds16(gA0, AsB +        wave*1024);
  glds16(gA1, AsB + 4096 + wave*1024);
  glds16(gB0, BsB +        wave*1024);
  glds16(gB1, BsB + 4096 + wave*1024);
  __syncthreads();

  const int NT = K >> 5;
  int cur = 0;
  for (int t2 = 0; t2 < NT; ++t2){
    const int nxt = cur ^ 1;
    if (t2 + 1 < NT){                       // wave-uniform branch
      const int kt = (t2 + 1) << 5;
      glds16(gA0 + kt, AsB + nxt*8192 +        wave*1024);
      glds16(gA1 + kt, AsB + nxt*8192 + 4096 + wave*1024);
      glds16(gB0 + kt, BsB + nxt*8192 +        wave*1024);
      glds16(gB1 + kt, BsB + nxt*8192 + 4096 + wave*1024);
    }
    bf16x8 fa[4], fb[4];
#pragma unroll
    for (int i = 0; i < 4; ++i){
      fa[i] = *(const bf16x8*)(AsB + cur*8192 + offA[i]);
      fb[i] = *(const bf16x8*)(BsB + cur*8192 + offB[i]);
    }
#pragma unroll
    for (int i = 0; i < 4; ++i)
#pragma unroll
      for (int j = 0; j < 4; ++j)
        acc[i][j] = __builtin_amdgcn_mfma_f32_16x16x32_bf16(fa[i], fb[j], acc[i][j], 0, 0, 0);
    __syncthreads();   // stage(t+1) landed; all waves done reading buf cur
    cur = nxt;
  }

#pragma unroll
  for (int i = 0; i < 4; ++i){
#pragma unroll
    for (int j = 0; j < 4; ++j){
      int cm = bm*128 + wm*64 + i*16 + (lane >> 4)*4;
      int cn = bn*128 + wn*64 + j*16 + (lane & 15);
      float bv = bias[cn];
#pragma unroll
      for (int r = 0; r < 4; ++r){
        float v = acc[i][j][r] + bv;
        if (EPI == 2) v = gelu_f(v);
        if (EPI == 1) ((float*)outp)[(size_t)(cm + r)*N + cn] = v;
        else          ((u16*)  outp)[(size_t)(cm + r)*N + cn] = f2bf(v);
      }
    }
  }
}

// ---------------- MFMA attention: 1 wave per (window, head), 4 waves/block ----
__global__ __launch_bounds__(256, 2) void attn_mfma(const u16* __restrict__ qkv,
      const float* __restrict__ rpb, const float* __restrict__ ls,
      u16* __restrict__ outp)
{
  __shared__ __align__(16) u16 Pl[4][64*72];   // per-wave P[64][72] (pitch 144B)
  __shared__ __align__(16) u16 Vl[4][32*72];   // per-wave Vt[32][72] (c-major)
  __shared__ unsigned char regid[64];
  const int tid  = threadIdx.x, lane = tid & 63, wave = tid >> 6;
  const int lc = lane & 15, lg = lane >> 4;
  const int pair = blockIdx.x*4 + wave;        // all 4 waves share one window
  const int win = pair >> 4, h = pair & 15;

  const u16* qb = qkv + (size_t)win*49*1536 + h*32;
  const u16* kb = qb + 512;
  const u16* vb = qb + 1024;

  if (tid < 49){
    int wi = win & 63, wh = wi >> 3, ww = wi & 7;
    int q7 = (tid*37) >> 8, r7 = tid - q7*7;
    int gh = wh*7 + q7, gw = ww*7 + r7;
    int rh = gh < 49 ? 0 : (gh < 53 ? 1 : 2);
    int rw = gw < 49 ? 0 : (gw < 53 ? 1 : 2);
    regid[tid] = (unsigned char)(rh*3 + rw);
  }

  // ---- stage V transposed: Vt[c][j], zero-padded j>=49 ----
  u16* V = &Vl[wave][0];
#pragma unroll
  for (int it = 0; it < 4; ++it){
    int ch = it*64 + lane;                 // 256 chunks = 64 rows x 4 octets
    int n = ch >> 2, oct = ch & 3;
    union { int4 i4; u16 s[8]; } v8;
    if (n < 49) v8.i4 = *(const int4*)(vb + (size_t)n*1536 + oct*8);
    else        v8.i4 = make_int4(0,0,0,0);
#pragma unroll
    for (int q = 0; q < 8; ++q) V[(oct*8 + q)*72 + n] = v8.s[q];
  }

  // ---- Q,K fragments direct from global + cosine normalize ----
  const float scale = __expf(fminf(ls[h], 4.6051702f));  // ln(100)
  bf16x8 qf[4], kf[4];
#pragma unroll
  for (int ti = 0; ti < 4; ++ti){
    const int n = ti*16 + lc;              // rows n>=49 are garbage; masked later
    {
      union { int4 i4; u16 s[8]; } raw;
      raw.i4 = *(const int4*)(qb + (size_t)n*1536 + lg*8);
      float f[8]; float ss = 0.f;
#pragma unroll
      for (int q = 0; q < 8; ++q){ f[q] = bf2f(raw.s[q]); ss += f[q]*f[q]; }
      ss += __shfl_xor(ss, 16); ss += __shfl_xor(ss, 32);
      const float inv = scale / fmaxf(sqrtf(ss), 1e-12f);
      union { short s[8]; bf16x8 v; } o;
#pragma unroll
      for (int q = 0; q < 8; ++q) o.s[q] = (short)f2bf(f[q]*inv);
      qf[ti] = o.v;
    }
    {
      union { int4 i4; u16 s[8]; } raw;
      raw.i4 = *(const int4*)(kb + (size_t)n*1536 + lg*8);
      float f[8]; float ss = 0.f;
#pragma unroll
      for (int q = 0; q < 8; ++q){ f[q] = bf2f(raw.s[q]); ss += f[q]*f[q]; }
      ss += __shfl_xor(ss, 16); ss += __shfl_xor(ss, 32);
      const float inv = 1.f / fmaxf(sqrtf(ss), 1e-12f);
      union { short s[8]; bf16x8 v; } o;
#pragma unroll
      for (int q = 0; q < 8; ++q) o.s[q] = (short)f2bf(f[q]*inv);
      kf[ti] = o.v;
    }
  }
  __syncthreads();   // regid (cross-wave) + V staging settled

  // ---- QK^T ----
  f32x4 acc[4][4];
#pragma unroll
  for (int i = 0; i < 4; ++i)
#pragma unroll
    for (int j = 0; j < 4; ++j) acc[i][j] = (f32x4){0.f,0.f,0.f,0.f};
#pragma unroll
  for (int i = 0; i < 4; ++i)
#pragma unroll
    for (int j = 0; j < 4; ++j)
      acc[i][j] = __builtin_amdgcn_mfma_f32_16x16x32_bf16(qf[i], kf[j], acc[i][j], 0, 0, 0);

  // ---- bias + mask + row softmax (row = one 16-lane group) -> P LDS ----
  u16* P = &Pl[wave][0];
  int rj[4];
#pragma unroll
  for (int tj = 0; tj < 4; ++tj){
    int j = tj*16 + lc;
    rj[tj] = (int)regid[j < 49 ? j : 0];
  }
  const float* rpbh = rpb + h*2401;
#pragma unroll
  for (int ti = 0; ti < 4; ++ti){
#pragma unroll
    for (int r = 0; r < 4; ++r){
      const int i = ti*16 + lg*4 + r;
      const bool iv = i < 49;
      const int ic = iv ? i : 0;
      const int ri = (int)regid[ic];
      const float* rrow = rpbh + ic*49;
      float sv[4];
#pragma unroll
      for (int tj = 0; tj < 4; ++tj){
        const int j = tj*16 + lc;
        float t2 = acc[ti][tj][r] + rrow[j < 49 ? j : 0];
        if (ri != rj[tj]) t2 -= 100.f;
        sv[tj] = (iv && j < 49) ? t2 : -1e30f;   // overwrite kills pad garbage/NaN
      }
      float mx = fmaxf(fmaxf(sv[0],sv[1]), fmaxf(sv[2],sv[3]));
      mx = fmaxf(mx, __shfl_xor(mx, 1));
      mx = fmaxf(mx, __shfl_xor(mx, 2));
      mx = fmaxf(mx, __shfl_xor(mx, 4));
      mx = fmaxf(mx, __shfl_xor(mx, 8));
      float p[4], sum = 0.f;
#pragma unroll
      for (int tj = 0; tj < 4; ++tj){ p[tj] = __expf(sv[tj] - mx); sum += p[tj]; }
      sum += __shfl_xor(sum, 1); sum += __shfl_xor(sum, 2);
      sum += __shfl_xor(sum, 4); sum += __shfl_xor(sum, 8);
      const float rs = __builtin_amdgcn_rcpf(sum);
#pragma unroll
      for (int tj = 0; tj < 4; ++tj) P[i*72 + tj*16 + lc] = f2bf(p[tj]*rs);
    }
  }
  __syncthreads();   // P visible

  // ---- PV ----
  f32x4 o[4][2];
#pragma unroll
  for (int i = 0; i < 4; ++i){ o[i][0] = (f32x4){0.f,0.f,0.f,0.f}; o[i][1] = (f32x4){0.f,0.f,0.f,0.f}; }
#pragma unroll
  for (int ks = 0; ks < 2; ++ks){
    bf16x8 pa[4], vf[2];
#pragma unroll
    for (int ti = 0; ti < 4; ++ti)
      pa[ti] = *(const bf16x8*)((const char*)P + (ti*16 + lc)*144 + (ks*4 + lg)*16);
#pragma unroll
    for (int tc = 0; tc < 2; ++tc)
      vf[tc] = *(const bf16x8*)((const char*)V + (tc*16 + lc)*144 + (ks*4 + lg)*16);
#pragma unroll
    for (int ti = 0; ti < 4; ++ti)
#pragma unroll
      for (int tc = 0; tc < 2; ++tc)
        o[ti][tc] = __builtin_amdgcn_mfma_f32_16x16x32_bf16(pa[ti], vf[tc], o[ti][tc], 0, 0, 0);
  }

  // ---- store (window order) ----
#pragma unroll
  for (int ti = 0; ti < 4; ++ti){
#pragma unroll
    for (int tc = 0; tc < 2; ++tc){
#pragma unroll
      for (int r = 0; r < 4; ++r){
        const int i = ti*16 + lg*4 + r;
        if (i < 49)
          outp[((size_t)win*49 + i)*512 + h*32 + tc*16 + lc] = f2bf(o[ti][tc][r]);
      }
    }
  }
}

// ---------------- LN kernels ----------------
__global__ __launch_bounds__(256) void ln1_kernel(const float* __restrict__ x,
      const u16* __restrict__ y, const float* __restrict__ g, const float* __restrict__ bt,
      float* __restrict__ xout, u16* __restrict__ xbf)
{
  __shared__ float red[8];
  const int t = blockIdx.x;
  const int b = t / 3136, s = t % 3136;
  const int hh = s / 56, ww2 = s % 56;
  int ph = hh + 53; if (ph >= 56) ph -= 56;   // inverse roll (+3)
  int pw = ww2 + 53; if (pw >= 56) pw -= 56;
  const int win = b*64 + (ph/7)*8 + (pw/7);
  const int n   = (ph%7)*7 + (pw%7);
  const u16* yr = y + ((size_t)win*49 + n)*512;
  const int c = threadIdx.x * 2;
  u32 u = *(const u32*)(yr + c);
  float vx = bf2f((u16)(u & 0xffff)), vy = bf2f((u16)(u >> 16));
  float sum = vx + vy, sq = vx*vx + vy*vy;
#pragma unroll
  for (int off = 32; off; off >>= 1){ sum += __shfl_xor(sum, off); sq += __shfl_xor(sq, off); }
  if ((threadIdx.x & 63) == 0){ red[threadIdx.x >> 6] = sum; red[(threadIdx.x >> 6) + 4] = sq; }
  __syncthreads();
  sum = red[0]+red[1]+red[2]+red[3];
  sq  = red[4]+red[5]+red[6]+red[7];
  const float mu  = sum * (1.f/512.f);
  const float inv = rsqrtf(fmaxf(sq * (1.f/512.f) - mu*mu, 0.f) + 1e-5f);
  const float* xr = x + (size_t)t*512;
  float2 xv = *(const float2*)(xr + c);
  float o0 = xv.x + (vx - mu)*inv*g[c]   + bt[c];
  float o1 = xv.y + (vy - mu)*inv*g[c+1] + bt[c+1];
  float* orow = xout + (size_t)t*512;
  orow[c] = o0; orow[c+1] = o1;
  *(u32*)(xbf + (size_t)t*512 + c) = (u32)f2bf(o0) | ((u32)f2bf(o1) << 16);
}

__global__ __launch_bounds__(256) void ln2_kernel(const u16* __restrict__ m,
      const float* __restrict__ g, const float* __restrict__ bt, float* __restrict__ out)
{
  __shared__ float red[8];
  const int t = blockIdx.x;
  const int c = threadIdx.x * 2;
  u32 u = *(const u32*)(m + (size_t)t*512 + c);
  float v0 = bf2f((u16)(u & 0xffff)), v1 = bf2f((u16)(u >> 16));
  float sum = v0 + v1, sq = v0*v0 + v1*v1;
#pragma unroll
  for (int off = 32; off; off >>= 1){ sum += __shfl_xor(sum, off); sq += __shfl_xor(sq, off); }
  if ((threadIdx.x & 63) == 0){ red[threadIdx.x >> 6] = sum; red[(threadIdx.x >> 6) + 4] = sq; }
  __syncthreads();
  sum = red[0]+red[1]+red[2]+red[3];
  sq  = red[4]+red[5]+red[6]+red[7];
  const float mu  = sum * (1.f/512.f);
  const float inv = rsqrtf(fmaxf(sq * (1.f/512.f) - mu*mu, 0.f) + 1e-5f);
  float* orow = out + (size_t)t*512;
  orow[c]   += (v0 - mu)*inv*g[c]   + bt[c];
  orow[c+1] += (v1 - mu)*inv*g[c+1] + bt[c+1];
}

// ---------------- tiny prep kernels ----------------
__global__ void cast_bf16_kernel(const float* __restrict__ in, u16* __restrict__ out, int n4){
  int i = blockIdx.x*256 + threadIdx.x;
  if (i >= n4) return;
  float4 v = *(const float4*)(in + (size_t)i*4);
  u32 lo = (u32)f2bf(v.x) | ((u32)f2bf(v.y) << 16);
  u32 hi = (u32)f2bf(v.z) | ((u32)f2bf(v.w) << 16);
  *(uint2*)(out + (size_t)i*4) = make_uint2(lo, hi);
}
__global__ void qkvbias_kernel(const float* __restrict__ qb, const float* __restrict__ vb,
                               float* __restrict__ out){
  int i = blockIdx.x*256 + threadIdx.x;
  if (i >= 1536) return;
  out[i] = i < 512 ? qb[i] : (i < 1024 ? 0.f : vb[i - 1024]);
}
__device__ __forceinline__ float cpb_coord(int d){
  float v = (float)(d - 6) * (8.f/6.f);
  float m = log2f(fabsf(v) + 1.f) * (1.f/3.f);     // log2(8)=3
  return v > 0.f ? m : (v < 0.f ? -m : 0.f);
}
__global__ void cpb_kernel(const float* __restrict__ w1, const float* __restrict__ b1,
                           const float* __restrict__ w2, float* __restrict__ btbl){
  int idx = blockIdx.x*256 + threadIdx.x;
  if (idx >= 169*16) return;
  int e = idx >> 4, h = idx & 15;
  float t0 = cpb_coord(e / 13), t1 = cpb_coord(e % 13);
  float acc = 0.f;
  for (int jj = 0; jj < 512; ++jj){
    float hid = fmaxf(t0*w1[jj*2] + t1*w1[jj*2+1] + b1[jj], 0.f);
    acc += hid * w2[h*512 + jj];
  }
  btbl[e*16 + h] = acc;
}
__global__ void rpb_kernel(const float* __restrict__ btbl, float* __restrict__ rpb){
  int idx = blockIdx.x*256 + threadIdx.x;
  if (idx >= 16*49*49) return;
  int hh = idx / 2401, ij = idx % 2401, i = ij / 49, j = ij % 49;
  int dr = i/7 - j/7 + 6, dc = i%7 - j%7 + 6;
  float bb = btbl[(dr*13 + dc)*16 + hh];
  rpb[idx] = 16.f / (1.f + __expf(-bb));
}

// ---------------- launch ----------------
extern "C" void kernel_launch(void* const* d_in, const int* in_sizes, int n_in,
                              void* d_out, int out_size, void* d_ws, size_t ws_size,
                              hipStream_t stream)
{
  const float* x    = (const float*)d_in[0];
  const float* qkvw = (const float*)d_in[1];
  const float* qb   = (const float*)d_in[2];
  const float* vb   = (const float*)d_in[3];
  const float* ls   = (const float*)d_in[4];
  const float* cw1  = (const float*)d_in[5];
  const float* cb1  = (const float*)d_in[6];
  const float* cw2  = (const float*)d_in[7];
  const float* pw   = (const float*)d_in[8];
  const float* pb   = (const float*)d_in[9];
  const float* n1g  = (const float*)d_in[10];
  const float* n1b  = (const float*)d_in[11];
  const float* f1w  = (const float*)d_in[12];
  const float* f1b  = (const float*)d_in[13];
  const float* f2w  = (const float*)d_in[14];
  const float* f2b  = (const float*)d_in[15];
  const float* n2g  = (const float*)d_in[16];
  const float* n2b  = (const float*)d_in[17];

  char* ws = (char*)d_ws;
  const size_t SZ_BIG = (size_t)100352 * 2048 * 2;   // 411 MB big region
  const size_t SZ_MID = (size_t)100352 * 512  * 2;   // 103 MB mid region
  size_t o = SZ_BIG + SZ_MID;
  u16* wqkv  = (u16*)(ws + o); o += (size_t)1536*512*2;
  u16* wproj = (u16*)(ws + o); o += (size_t)512*512*2;
  u16* wfc1  = (u16*)(ws + o); o += (size_t)2048*512*2;
  u16* wfc2  = (u16*)(ws + o); o += (size_t)512*2048*2;
  float* qkvbias = (float*)(ws + o); o += 1536*4;
  float* btbl    = (float*)(ws + o); o += 2704*4;
  float* rpb     = (float*)(ws + o); o += 38416*4;

  // big-region phases: [xbf 103MB | qkv 308MB] -> [y_h 103MB] -> [fc1-out 411MB]
  u16*   xbf   = (u16*)ws;
  u16*   qkvo  = (u16*)(ws + (size_t)100352*512*2);
  u16*   y_h   = (u16*)ws;
  u16*   big_h = (u16*)ws;
  u16*   mid   = (u16*)(ws + SZ_BIG);
  float* out   = (float*)d_out;

  cast_bf16_kernel<<<768,  256, 0, stream>>>(qkvw, wqkv, 1536*512/4);
  cast_bf16_kernel<<<256,  256, 0, stream>>>(pw,  wproj, 512*512/4);
  cast_bf16_kernel<<<1024, 256, 0, stream>>>(f1w, wfc1, 2048*512/4);
  cast_bf16_kernel<<<1024, 256, 0, stream>>>(f2w, wfc2, 512*2048/4);
  qkvbias_kernel<<<6, 256, 0, stream>>>(qb, vb, qkvbias);
  cpb_kernel<<<11, 256, 0, stream>>>(cw1, cb1, cw2, btbl);
  rpb_kernel<<<151, 256, 0, stream>>>(btbl, rpb);
  cast_bf16_kernel<<<50176, 256, 0, stream>>>(x, xbf, 100352*512/4);

  // QKV: row-gathered A (roll+window fused), gload_lds staging
  gemm_bt<0,2><<<784*12, 256, 0, stream>>>(xbf, wqkv, qkvbias,
                                           (void*)qkvo, 100352, 1536, 512, 12);
  attn_mfma<<<8192, 256, 0, stream>>>(qkvo, rpb, ls, mid);
  // proj -> bf16 (window order)
  gemm_bt<0,0><<<784*4, 256, 0, stream>>>(mid, wproj, pb,
                                          (void*)y_h, 100352, 512, 512, 4);
  // x2 = x + LN(unroll(y));  writes d_out (f32) + mid (bf16)
  ln1_kernel<<<100352, 256, 0, stream>>>(x, y_h, n1g, n1b, out, mid);
  // MLP
  gemm_bt<2,0><<<784*16, 256, 0, stream>>>(mid, wfc1, f1b,
                                           (void*)big_h, 100352, 2048, 512, 16);
  gemm_bt<0,0><<<784*4, 256, 0, stream>>>(big_h, wfc2, f2b,
                                          (void*)mid, 100352, 512, 2048, 4);
  // out += LN(m)
  ln2_kernel<<<100352, 256, 0, stream>>>(mid, n2g, n2b, out);
}

// Round 5
// 1502.239 us; speedup vs baseline: 1.9762x; 1.0009x over previous
//
#include <hip/hip_runtime.h>

typedef unsigned short u16;
typedef unsigned int   u32;

using f32x4  = __attribute__((ext_vector_type(4))) float;
using bf16x8 = __attribute__((ext_vector_type(8))) short;  // 8 bf16 in 4 VGPRs

__device__ __forceinline__ float bf2f(u16 u){
  union { u32 i; float f; } x; x.i = ((u32)u) << 16; return x.f;
}
__device__ __forceinline__ u16 f2bf(float f){
  union { float f; u32 i; } x; x.f = f;
  u32 r = x.i + 0x7FFFu + ((x.i >> 16) & 1u);   // RNE
  return (u16)(r >> 16);
}
// tanh-form GELU, safe at +/-inf exp: tanh(u) = 1 - 2/(e^{2u}+1)
__device__ __forceinline__ float gelu_f(float v){
  float u = 0.7978845608f * v * (1.f + 0.044715f*v*v);
  float e = __expf(2.f*u);
  return 0.5f*v*(2.f - 2.f/(e + 1.f));
}

// async global->LDS, 16B per lane. LDS dest = wave-uniform base + lane*16 (HW);
// global source address is per-lane (enables row-gather staging).
__device__ __forceinline__ void glds16(const void* g, void* l){
  __builtin_amdgcn_global_load_lds(
      (const __attribute__((address_space(1))) unsigned int*)g,
      (__attribute__((address_space(3))) unsigned int*)(unsigned int)(unsigned long long)l,
      16, 0, 0);
}

// window-order token m -> source row in x (roll by -3,-3 then 7x7 window partition)
__device__ __forceinline__ int rollmap(int m){
  int win = m / 49, n = m % 49;
  int b  = win >> 6, wi = win & 63;
  int wh = wi >> 3, ww = wi & 7;
  int r = n / 7, c = n % 7;
  int sh = wh*7 + r + 3; if (sh >= 56) sh -= 56;
  int sw = ww*7 + c + 3; if (sw >= 56) sw -= 56;
  return b*3136 + sh*56 + sw;
}

// ---------------- GEMM: C[M,N] = A[M,K] @ W[N,K]^T + bias ----------------
// AMODE 0: A bf16 row-major.  AMODE 2: A bf16 with roll/window row-gather.
// global_load_lds staging, 3-buffer depth-2 pipeline, counted vmcnt (T3+T4):
// steady-state wait is vmcnt(4) -- the newest stage's 4 loads stay in flight
// across the barrier, giving each stage ~2 iterations to cover HBM latency.
// EPI 0: bf16 out. EPI 1: f32 out. EPI 2: bf16 out + GELU.
template<int EPI, int AMODE>
__global__ __launch_bounds__(256) void gemm_bt(const u16* __restrict__ A,
      const u16* __restrict__ Bw, const float* __restrict__ bias,
      void* __restrict__ outp, int M, int N, int K, int nbn)
{
  __shared__ __align__(16) char LDS[3*16384];   // 3 bufs x (A 8KB + B 8KB) = 48 KB
  const int t    = threadIdx.x;
  const int lane = t & 63, wave = t >> 6;
  const int wm = wave >> 1, wn = wave & 1;

  // XCD-chunked block swizzle; bn fastest so blocks sharing an A-tile are adjacent.
  const int gl = ((blockIdx.x & 7) * ((int)gridDim.x >> 3)) + (blockIdx.x >> 3);
  const int bm = gl / nbn, bn = gl - bm*nbn;

  const int r0 = t >> 2;     // tile row 0..63 (and +64 for second half)
  const int sc = t & 3;      // this thread's LDS slot chunk (linear dest)
  const int dc = sc ^ ((r0 >> 1) & 3);   // data chunk to fetch -> lands swizzled

  const u16* gB0 = Bw + (size_t)(bn*128 + r0)*K + dc*8;
  const u16* gB1 = gB0 + (size_t)64*K;
  const u16* gA0; const u16* gA1;
  if constexpr (AMODE == 0){
    gA0 = A + (size_t)(bm*128 + r0)*K + dc*8;
    gA1 = gA0 + (size_t)64*K;
  } else {
    gA0 = A + (size_t)rollmap(bm*128 + r0     )*K + dc*8;
    gA1 = A + (size_t)rollmap(bm*128 + r0 + 64)*K + dc*8;
  }

  const int lr = lane & 15, lk = lane >> 4;
  int offA[4], offB[4];
#pragma unroll
  for (int i = 0; i < 4; ++i){
    int ar = wm*64 + i*16 + lr;
    offA[i] = ar*64 + ((lk ^ ((ar >> 1) & 3)) * 16);
    int br = wn*64 + i*16 + lr;
    offB[i] = br*64 + ((lk ^ ((br >> 1) & 3)) * 16);
  }

  f32x4 acc[4][4];
#pragma unroll
  for (int i = 0; i < 4; ++i)
#pragma unroll
    for (int j = 0; j < 4; ++j) acc[i][j] = (f32x4){0.f, 0.f, 0.f, 0.f};

  auto STAGE = [&](int kt, int buf){
    char* Ld = LDS + buf*16384;
    glds16(gA0 + kt, Ld +         wave*1024);
    glds16(gA1 + kt, Ld +  4096 + wave*1024);
    glds16(gB0 + kt, Ld +  8192 + wave*1024);
    glds16(gB1 + kt, Ld + 12288 + wave*1024);
  };
  auto COMPUTE = [&](int buf){
    const char* Ld = LDS + buf*16384;
    bf16x8 fa[4], fb[4];
#pragma unroll
    for (int i = 0; i < 4; ++i){
      fa[i] = *(const bf16x8*)(Ld + offA[i]);
      fb[i] = *(const bf16x8*)(Ld + 8192 + offB[i]);
    }
#pragma unroll
    for (int i = 0; i < 4; ++i)
#pragma unroll
      for (int j = 0; j < 4; ++j)
        acc[i][j] = __builtin_amdgcn_mfma_f32_16x16x32_bf16(fa[i], fb[j], acc[i][j], 0, 0, 0);
  };

  const int NT = K >> 5;                 // always >= 16 here
  STAGE(0, 0);
  STAGE(32, 1);
  asm volatile("s_waitcnt vmcnt(4)" ::: "memory");   // own stage-0 done
  __builtin_amdgcn_s_barrier();
  asm volatile("" ::: "memory");                     // pin reads below barrier
  int cur = 0;
  for (int t2 = 0; t2 + 2 < NT; ++t2){
    int nx2 = cur + 2; if (nx2 >= 3) nx2 -= 3;
    STAGE((t2 + 2) << 5, nx2);
    COMPUTE(cur);
    // stage(t+1) landed (oldest 4 of 8); stage(t+2) stays in flight.
    // lgkmcnt(0): own ds_reads done -> buffer re-staged next iter is safe.
    asm volatile("s_waitcnt vmcnt(4) lgkmcnt(0)" ::: "memory");
    __builtin_amdgcn_s_barrier();
    asm volatile("" ::: "memory");
    ++cur; if (cur == 3) cur = 0;
  }
  COMPUTE(cur);
  asm volatile("s_waitcnt vmcnt(0) lgkmcnt(0)" ::: "memory");
  __builtin_amdgcn_s_barrier();
  asm volatile("" ::: "memory");
  ++cur; if (cur == 3) cur = 0;
  COMPUTE(cur);

#pragma unroll
  for (int i = 0; i < 4; ++i){
#pragma unroll
    for (int j = 0; j < 4; ++j){
      int cm = bm*128 + wm*64 + i*16 + (lane >> 4)*4;
      int cn = bn*128 + wn*64 + j*16 + (lane & 15);
      float bv = bias[cn];
#pragma unroll
      for (int r = 0; r < 4; ++r){
        float v = acc[i][j][r] + bv;
        if (EPI == 2) v = gelu_f(v);
        if (EPI == 1) ((float*)outp)[(size_t)(cm + r)*N + cn] = v;
        else          ((u16*)  outp)[(size_t)(cm + r)*N + cn] = f2bf(v);
      }
    }
  }
}

// ---------------- MFMA attention: 1 wave per (window, head), 4 waves/block ----
__global__ __launch_bounds__(256, 2) void attn_mfma(const u16* __restrict__ qkv,
      const float* __restrict__ rpb, const float* __restrict__ ls,
      u16* __restrict__ outp)
{
  __shared__ __align__(16) u16 Pl[4][64*72];   // per-wave P[64][72] (pitch 144B)
  __shared__ __align__(16) u16 Vl[4][32*72];   // per-wave Vt[32][72] (c-major)
  __shared__ unsigned char regid[64];
  const int tid  = threadIdx.x, lane = tid & 63, wave = tid >> 6;
  const int lc = lane & 15, lg = lane >> 4;
  const int pair = blockIdx.x*4 + wave;        // all 4 waves share one window
  const int win = pair >> 4, h = pair & 15;

  const u16* qb = qkv + (size_t)win*49*1536 + h*32;
  const u16* kb = qb + 512;
  const u16* vb = qb + 1024;

  if (tid < 49){
    int wi = win & 63, wh = wi >> 3, ww = wi & 7;
    int q7 = (tid*37) >> 8, r7 = tid - q7*7;
    int gh = wh*7 + q7, gw = ww*7 + r7;
    int rh = gh < 49 ? 0 : (gh < 53 ? 1 : 2);
    int rw = gw < 49 ? 0 : (gw < 53 ? 1 : 2);
    regid[tid] = (unsigned char)(rh*3 + rw);
  }

  // ---- stage V transposed: Vt[c][j], zero-padded j>=49 ----
  u16* V = &Vl[wave][0];
#pragma unroll
  for (int it = 0; it < 4; ++it){
    int ch = it*64 + lane;                 // 256 chunks = 64 rows x 4 octets
    int n = ch >> 2, oct = ch & 3;
    union { int4 i4; u16 s[8]; } v8;
    if (n < 49) v8.i4 = *(const int4*)(vb + (size_t)n*1536 + oct*8);
    else        v8.i4 = make_int4(0,0,0,0);
#pragma unroll
    for (int q = 0; q < 8; ++q) V[(oct*8 + q)*72 + n] = v8.s[q];
  }

  // ---- Q,K fragments direct from global + cosine normalize ----
  const float scale = __expf(fminf(ls[h], 4.6051702f));  // ln(100)
  bf16x8 qf[4], kf[4];
#pragma unroll
  for (int ti = 0; ti < 4; ++ti){
    const int n = ti*16 + lc;              // rows n>=49 are garbage; masked later
    {
      union { int4 i4; u16 s[8]; } raw;
      raw.i4 = *(const int4*)(qb + (size_t)n*1536 + lg*8);
      float f[8]; float ss = 0.f;
#pragma unroll
      for (int q = 0; q < 8; ++q){ f[q] = bf2f(raw.s[q]); ss += f[q]*f[q]; }
      ss += __shfl_xor(ss, 16); ss += __shfl_xor(ss, 32);
      const float inv = scale / fmaxf(sqrtf(ss), 1e-12f);
      union { short s[8]; bf16x8 v; } o;
#pragma unroll
      for (int q = 0; q < 8; ++q) o.s[q] = (short)f2bf(f[q]*inv);
      qf[ti] = o.v;
    }
    {
      union { int4 i4; u16 s[8]; } raw;
      raw.i4 = *(const int4*)(kb + (size_t)n*1536 + lg*8);
      float f[8]; float ss = 0.f;
#pragma unroll
      for (int q = 0; q < 8; ++q){ f[q] = bf2f(raw.s[q]); ss += f[q]*f[q]; }
      ss += __shfl_xor(ss, 16); ss += __shfl_xor(ss, 32);
      const float inv = 1.f / fmaxf(sqrtf(ss), 1e-12f);
      union { short s[8]; bf16x8 v; } o;
#pragma unroll
      for (int q = 0; q < 8; ++q) o.s[q] = (short)f2bf(f[q]*inv);
      kf[ti] = o.v;
    }
  }
  __syncthreads();   // regid (cross-wave) + V staging settled

  // ---- QK^T ----
  f32x4 acc[4][4];
#pragma unroll
  for (int i = 0; i < 4; ++i)
#pragma unroll
    for (int j = 0; j < 4; ++j) acc[i][j] = (f32x4){0.f,0.f,0.f,0.f};
#pragma unroll
  for (int i = 0; i < 4; ++i)
#pragma unroll
    for (int j = 0; j < 4; ++j)
      acc[i][j] = __builtin_amdgcn_mfma_f32_16x16x32_bf16(qf[i], kf[j], acc[i][j], 0, 0, 0);

  // ---- bias + mask + row softmax (row = one 16-lane group) -> P LDS ----
  u16* P = &Pl[wave][0];
  int rj[4];
#pragma unroll
  for (int tj = 0; tj < 4; ++tj){
    int j = tj*16 + lc;
    rj[tj] = (int)regid[j < 49 ? j : 0];
  }
  const float* rpbh = rpb + h*2401;
#pragma unroll
  for (int ti = 0; ti < 4; ++ti){
#pragma unroll
    for (int r = 0; r < 4; ++r){
      const int i = ti*16 + lg*4 + r;
      const bool iv = i < 49;
      const int ic = iv ? i : 0;
      const int ri = (int)regid[ic];
      const float* rrow = rpbh + ic*49;
      float sv[4];
#pragma unroll
      for (int tj = 0; tj < 4; ++tj){
        const int j = tj*16 + lc;
        float t2 = acc[ti][tj][r] + rrow[j < 49 ? j : 0];
        if (ri != rj[tj]) t2 -= 100.f;
        sv[tj] = (iv && j < 49) ? t2 : -1e30f;   // overwrite kills pad garbage/NaN
      }
      float mx = fmaxf(fmaxf(sv[0],sv[1]), fmaxf(sv[2],sv[3]));
      mx = fmaxf(mx, __shfl_xor(mx, 1));
      mx = fmaxf(mx, __shfl_xor(mx, 2));
      mx = fmaxf(mx, __shfl_xor(mx, 4));
      mx = fmaxf(mx, __shfl_xor(mx, 8));
      float p[4], sum = 0.f;
#pragma unroll
      for (int tj = 0; tj < 4; ++tj){ p[tj] = __expf(sv[tj] - mx); sum += p[tj]; }
      sum += __shfl_xor(sum, 1); sum += __shfl_xor(sum, 2);
      sum += __shfl_xor(sum, 4); sum += __shfl_xor(sum, 8);
      const float rs = __builtin_amdgcn_rcpf(sum);
#pragma unroll
      for (int tj = 0; tj < 4; ++tj) P[i*72 + tj*16 + lc] = f2bf(p[tj]*rs);
    }
  }
  __syncthreads();   // P visible

  // ---- PV ----
  f32x4 o[4][2];
#pragma unroll
  for (int i = 0; i < 4; ++i){ o[i][0] = (f32x4){0.f,0.f,0.f,0.f}; o[i][1] = (f32x4){0.f,0.f,0.f,0.f}; }
#pragma unroll
  for (int ks = 0; ks < 2; ++ks){
    bf16x8 pa[4], vf[2];
#pragma unroll
    for (int ti = 0; ti < 4; ++ti)
      pa[ti] = *(const bf16x8*)((const char*)P + (ti*16 + lc)*144 + (ks*4 + lg)*16);
#pragma unroll
    for (int tc = 0; tc < 2; ++tc)
      vf[tc] = *(const bf16x8*)((const char*)V + (tc*16 + lc)*144 + (ks*4 + lg)*16);
#pragma unroll
    for (int ti = 0; ti < 4; ++ti)
#pragma unroll
      for (int tc = 0; tc < 2; ++tc)
        o[ti][tc] = __builtin_amdgcn_mfma_f32_16x16x32_bf16(pa[ti], vf[tc], o[ti][tc], 0, 0, 0);
  }

  // ---- store (window order) ----
#pragma unroll
  for (int ti = 0; ti < 4; ++ti){
#pragma unroll
    for (int tc = 0; tc < 2; ++tc){
#pragma unroll
      for (int r = 0; r < 4; ++r){
        const int i = ti*16 + lg*4 + r;
        if (i < 49)
          outp[((size_t)win*49 + i)*512 + h*32 + tc*16 + lc] = f2bf(o[ti][tc][r]);
      }
    }
  }
}

// ---------------- LN kernels ----------------
__global__ __launch_bounds__(256) void ln1_kernel(const float* __restrict__ x,
      const u16* __restrict__ y, const float* __restrict__ g, const float* __restrict__ bt,
      float* __restrict__ xout, u16* __restrict__ xbf)
{
  __shared__ float red[8];
  const int t = blockIdx.x;
  const int b = t / 3136, s = t % 3136;
  const int hh = s / 56, ww2 = s % 56;
  int ph = hh + 53; if (ph >= 56) ph -= 56;   // inverse roll (+3)
  int pw = ww2 + 53; if (pw >= 56) pw -= 56;
  const int win = b*64 + (ph/7)*8 + (pw/7);
  const int n   = (ph%7)*7 + (pw%7);
  const u16* yr = y + ((size_t)win*49 + n)*512;
  const int c = threadIdx.x * 2;
  u32 u = *(const u32*)(yr + c);
  float vx = bf2f((u16)(u & 0xffff)), vy = bf2f((u16)(u >> 16));
  float sum = vx + vy, sq = vx*vx + vy*vy;
#pragma unroll
  for (int off = 32; off; off >>= 1){ sum += __shfl_xor(sum, off); sq += __shfl_xor(sq, off); }
  if ((threadIdx.x & 63) == 0){ red[threadIdx.x >> 6] = sum; red[(threadIdx.x >> 6) + 4] = sq; }
  __syncthreads();
  sum = red[0]+red[1]+red[2]+red[3];
  sq  = red[4]+red[5]+red[6]+red[7];
  const float mu  = sum * (1.f/512.f);
  const float inv = rsqrtf(fmaxf(sq * (1.f/512.f) - mu*mu, 0.f) + 1e-5f);
  const float* xr = x + (size_t)t*512;
  float2 xv = *(const float2*)(xr + c);
  float o0 = xv.x + (vx - mu)*inv*g[c]   + bt[c];
  float o1 = xv.y + (vy - mu)*inv*g[c+1] + bt[c+1];
  float* orow = xout + (size_t)t*512;
  orow[c] = o0; orow[c+1] = o1;
  *(u32*)(xbf + (size_t)t*512 + c) = (u32)f2bf(o0) | ((u32)f2bf(o1) << 16);
}

__global__ __launch_bounds__(256) void ln2_kernel(const u16* __restrict__ m,
      const float* __restrict__ g, const float* __restrict__ bt, float* __restrict__ out)
{
  __shared__ float red[8];
  const int t = blockIdx.x;
  const int c = threadIdx.x * 2;
  u32 u = *(const u32*)(m + (size_t)t*512 + c);
  float v0 = bf2f((u16)(u & 0xffff)), v1 = bf2f((u16)(u >> 16));
  float sum = v0 + v1, sq = v0*v0 + v1*v1;
#pragma unroll
  for (int off = 32; off; off >>= 1){ sum += __shfl_xor(sum, off); sq += __shfl_xor(sq, off); }
  if ((threadIdx.x & 63) == 0){ red[threadIdx.x >> 6] = sum; red[(threadIdx.x >> 6) + 4] = sq; }
  __syncthreads();
  sum = red[0]+red[1]+red[2]+red[3];
  sq  = red[4]+red[5]+red[6]+red[7];
  const float mu  = sum * (1.f/512.f);
  const float inv = rsqrtf(fmaxf(sq * (1.f/512.f) - mu*mu, 0.f) + 1e-5f);
  float* orow = out + (size_t)t*512;
  orow[c]   += (v0 - mu)*inv*g[c]   + bt[c];
  orow[c+1] += (v1 - mu)*inv*g[c+1] + bt[c+1];
}

// ---------------- tiny prep kernels ----------------
__global__ void cast_bf16_kernel(const float* __restrict__ in, u16* __restrict__ out, int n4){
  int i = blockIdx.x*256 + threadIdx.x;
  if (i >= n4) return;
  float4 v = *(const float4*)(in + (size_t)i*4);
  u32 lo = (u32)f2bf(v.x) | ((u32)f2bf(v.y) << 16);
  u32 hi = (u32)f2bf(v.z) | ((u32)f2bf(v.w) << 16);
  *(uint2*)(out + (size_t)i*4) = make_uint2(lo, hi);
}
__global__ void qkvbias_kernel(const float* __restrict__ qb, const float* __restrict__ vb,
                               float* __restrict__ out){
  int i = blockIdx.x*256 + threadIdx.x;
  if (i >= 1536) return;
  out[i] = i < 512 ? qb[i] : (i < 1024 ? 0.f : vb[i - 1024]);
}
__device__ __forceinline__ float cpb_coord(int d){
  float v = (float)(d - 6) * (8.f/6.f);
  float m = log2f(fabsf(v) + 1.f) * (1.f/3.f);     // log2(8)=3
  return v > 0.f ? m : (v < 0.f ? -m : 0.f);
}
__global__ void cpb_kernel(const float* __restrict__ w1, const float* __restrict__ b1,
                           const float* __restrict__ w2, float* __restrict__ btbl){
  int idx = blockIdx.x*256 + threadIdx.x;
  if (idx >= 169*16) return;
  int e = idx >> 4, h = idx & 15;
  float t0 = cpb_coord(e / 13), t1 = cpb_coord(e % 13);
  float acc = 0.f;
  for (int jj = 0; jj < 512; ++jj){
    float hid = fmaxf(t0*w1[jj*2] + t1*w1[jj*2+1] + b1[jj], 0.f);
    acc += hid * w2[h*512 + jj];
  }
  btbl[e*16 + h] = acc;
}
__global__ void rpb_kernel(const float* __restrict__ btbl, float* __restrict__ rpb){
  int idx = blockIdx.x*256 + threadIdx.x;
  if (idx >= 16*49*49) return;
  int hh = idx / 2401, ij = idx % 2401, i = ij / 49, j = ij % 49;
  int dr = i/7 - j/7 + 6, dc = i%7 - j%7 + 6;
  float bb = btbl[(dr*13 + dc)*16 + hh];
  rpb[idx] = 16.f / (1.f + __expf(-bb));
}

// ---------------- launch ----------------
extern "C" void kernel_launch(void* const* d_in, const int* in_sizes, int n_in,
                              void* d_out, int out_size, void* d_ws, size_t ws_size,
                              hipStream_t stream)
{
  const float* x    = (const float*)d_in[0];
  const float* qkvw = (const float*)d_in[1];
  const float* qb   = (const float*)d_in[2];
  const float* vb   = (const float*)d_in[3];
  const float* ls   = (const float*)d_in[4];
  const float* cw1  = (const float*)d_in[5];
  const float* cb1  = (const float*)d_in[6];
  const float* cw2  = (const float*)d_in[7];
  const float* pw   = (const float*)d_in[8];
  const float* pb   = (const float*)d_in[9];
  const float* n1g  = (const float*)d_in[10];
  const float* n1b  = (const float*)d_in[11];
  const float* f1w  = (const float*)d_in[12];
  const float* f1b  = (const float*)d_in[13];
  const float* f2w  = (const float*)d_in[14];
  const float* f2b  = (const float*)d_in[15];
  const float* n2g  = (const float*)d_in[16];
  const float* n2b  = (const float*)d_in[17];

  char* ws = (char*)d_ws;
  const size_t SZ_BIG = (size_t)100352 * 2048 * 2;   // 411 MB big region
  const size_t SZ_MID = (size_t)100352 * 512  * 2;   // 103 MB mid region
  size_t o = SZ_BIG + SZ_MID;
  u16* wqkv  = (u16*)(ws + o); o += (size_t)1536*512*2;
  u16* wproj = (u16*)(ws + o); o += (size_t)512*512*2;
  u16* wfc1  = (u16*)(ws + o); o += (size_t)2048*512*2;
  u16* wfc2  = (u16*)(ws + o); o += (size_t)512*2048*2;
  float* qkvbias = (float*)(ws + o); o += 1536*4;
  float* btbl    = (float*)(ws + o); o += 2704*4;
  float* rpb     = (float*)(ws + o); o += 38416*4;

  // big-region phases: [xbf 103MB | qkv 308MB] -> [y_h 103MB] -> [fc1-out 411MB]
  u16*   xbf   = (u16*)ws;
  u16*   qkvo  = (u16*)(ws + (size_t)100352*512*2);
  u16*   y_h   = (u16*)ws;
  u16*   big_h = (u16*)ws;
  u16*   mid   = (u16*)(ws + SZ_BIG);
  float* out   = (float*)d_out;

  cast_bf16_kernel<<<768,  256, 0, stream>>>(qkvw, wqkv, 1536*512/4);
  cast_bf16_kernel<<<256,  256, 0, stream>>>(pw,  wproj, 512*512/4);
  cast_bf16_kernel<<<1024, 256, 0, stream>>>(f1w, wfc1, 2048*512/4);
  cast_bf16_kernel<<<1024, 256, 0, stream>>>(f2w, wfc2, 512*2048/4);
  qkvbias_kernel<<<6, 256, 0, stream>>>(qb, vb, qkvbias);
  cpb_kernel<<<11, 256, 0, stream>>>(cw1, cb1, cw2, btbl);
  rpb_kernel<<<151, 256, 0, stream>>>(btbl, rpb);
  cast_bf16_kernel<<<50176, 256, 0, stream>>>(x, xbf, 100352*512/4);

  // QKV: row-gathered A (roll+window fused), gload_lds staging
  gemm_bt<0,2><<<784*12, 256, 0, stream>>>(xbf, wqkv, qkvbias,
                                           (void*)qkvo, 100352, 1536, 512, 12);
  attn_mfma<<<8192, 256, 0, stream>>>(qkvo, rpb, ls, mid);
  // proj -> bf16 (window order)
  gemm_bt<0,0><<<784*4, 256, 0, stream>>>(mid, wproj, pb,
                                          (void*)y_h, 100352, 512, 512, 4);
  // x2 = x + LN(unroll(y));  writes d_out (f32) + mid (bf16)
  ln1_kernel<<<100352, 256, 0, stream>>>(x, y_h, n1g, n1b, out, mid);
  // MLP
  gemm_bt<2,0><<<784*16, 256, 0, stream>>>(mid, wfc1, f1b,
                                           (void*)big_h, 100352, 2048, 512, 16);
  gemm_bt<0,0><<<784*4, 256, 0, stream>>>(big_h, wfc2, f2b,
                                          (void*)mid, 100352, 512, 2048, 4);
  // out += LN(m)
  ln2_kernel<<<100352, 256, 0, stream>>>(mid, n2g, n2b, out);
}